// Round 4
// baseline (224.112 us; speedup 1.0000x reference)
//
#include <hip/hip_runtime.h>
#include <hip/hip_bf16.h>
#include <math.h>

// Problem constants
#define Tn 30
#define Bn 16384
#define Hn 100
#define Pn 7

// Tiling: gates padded 100->128 units => N=512 (32 n-tiles); K padded 100->128 (4 k-tiles of 32).
// K slots 100/101 carry the FC1 fold: A[k=100]=x_t(row), A[k=101]=1.0 (maintained by wave 6,
// whose unit columns 100..111 are padding); Whh1 B rows 100/101 hold u1[j]/wc1[j].
// 32 rows/block (grid 512), 8 waves; wave w owns units [16w,16w+16); wave 7 idle in phase 1,
// runs FC2 in phase 2. __launch_bounds__(512,4): 128 total regs/wave (64 arch + 64 acc for bf)
// => 2 blocks/CU = 4 waves/SIMD. Round-4: x staged as bf16 in LDS (kills float4 + per-step cvt),
// f2bf via v_cvt (RNE, identical bits) -> arch live set fits 64, no scratch spill.
#define ROWS 32           // rows per block
#define RGn 2             // row-groups of 16
#define KP 136            // h row pitch (ushorts); 272B -> 16B-aligned A-frag reads
#define RP 36             // gin2 row pitch (ushorts): 32 rows + 4 pad
#define NFRAG 128         // B-frags per matrix (32 nt x 4 kt)
#define FRAG_BYTES (NFRAG * 64 * 16)   // 131072 per matrix
#define WS_W2_OFF (3 * FRAG_BYTES)     // 28 W2 frags (7 ps x 4 kt)
#define HBUF_USH (ROWS * KP)           // 4352
#define G2_USH (512 * RP)              // 18432
#define XL_USH_OFF (2 * HBUF_USH + G2_USH)            // 27136 ushorts
#define SMEM_BYTES (XL_USH_OFF * 2 + Tn * ROWS * 2)   // 54272 + 1920 = 56192

#define PACK_BLOCKS 103   // (3*128*64 + 28*64)/256 exactly

typedef __attribute__((ext_vector_type(8))) short short8;   // 8 bf16 (4 VGPRs)
typedef __attribute__((ext_vector_type(4))) float floatx4;  // MFMA C/D
typedef __attribute__((ext_vector_type(4))) unsigned short ushortx4;

__device__ __forceinline__ float rcp_(float v) { return __builtin_amdgcn_rcpf(v); }
__device__ __forceinline__ float sig_(float v) { return rcp_(1.0f + __expf(-v)); }
__device__ __forceinline__ float tanh_(float v) { return 1.0f - 2.0f * rcp_(__expf(2.0f * v) + 1.0f); }
// cold-path manual RNE (setup kernel)
__device__ __forceinline__ unsigned short f2bf(float v) {
    unsigned int u = __float_as_uint(v);
    return (unsigned short)((u + 0x7FFFu + ((u >> 16) & 1u)) >> 16);   // RNE
}
// hot-path: hardware cvt (RNE, bit-identical to f2bf for finite inputs)
__device__ __forceinline__ unsigned short f2bf_i(float v) {
    __hip_bfloat16 b = __float2bfloat16(v);
    union { __hip_bfloat16 h; unsigned short u; } cv;
    cv.h = b;
    return cv.u;
}

// Pack the 3 recurrent matrices (400x100) into bf16 B-frag layout (gates padded to 128 units),
// with the bias/FC1 folds in padded K rows:
//   mat 0 (Whh1): k=100 -> u1[j] = Wih1[j,:]·W1 ; k=101 -> wc1[j] = Wih1[j,:]·b1 + bih1[j] + bhh1[j]
//   mat 1 (Wih2): k=101 -> bih2[j] + bhh2[j]
//   W2 frags:     k=101 && ps==6 -> b2[p]   (A k=101 is 1.0 every step; add bias exactly once)
// B[k][n]: n = lane&15, k = (lane>>4)*8 + jj  (16x16x32 bf16 B mapping, HW-verified).
__global__ void setup_kernel(const float* __restrict__ W1,
                             const float* __restrict__ b1,
                             const float* __restrict__ Wih1,
                             const float* __restrict__ bih1,
                             const float* __restrict__ bhh1,
                             const float* __restrict__ bih2,
                             const float* __restrict__ bhh2,
                             const float* __restrict__ Whh1,
                             const float* __restrict__ Wih2,
                             const float* __restrict__ Whh2,
                             const float* __restrict__ W2,
                             const float* __restrict__ b2,
                             float* __restrict__ ws) {
    int gid = blockIdx.x * 256 + threadIdx.x;   // 3*128*64 + 28*64 = 26368
    int lane = gid & 63;
    int l = lane & 15, q = lane >> 4;
    unsigned short hh[8];
    uint4 u;
    if (gid < 3 * NFRAG * 64) {
        int mat = gid / (NFRAG * 64);
        int f = (gid % (NFRAG * 64)) >> 6;
        int nt = f >> 2, kt = f & 3;
        int G = nt >> 3, ag = nt & 7;
        int j = ag * 16 + l;                    // unit within gate
        int row = G * Hn + (j < Hn ? j : 0);    // row of the 400-row weight matrices
        const float* W = (mat == 0) ? Whh1 : (mat == 1) ? Wih2 : Whh2;
        const float* wrow = W + row * Hn;
        float u1 = 0.f, wc1 = 0.f;
        if (mat == 0 && kt == 3 && q == 0 && j < Hn) {   // lanes producing k=100/101
            for (int k = 0; k < Hn; ++k) {
                float a = Wih1[row * Hn + k];
                u1 += a * W1[k];
                wc1 += a * b1[k];
            }
            wc1 += bih1[row] + bhh1[row];
        }
        int kbase = kt * 32 + q * 8;
#pragma unroll
        for (int jj = 0; jj < 8; ++jj) {
            int k = kbase + jj;
            unsigned short v = 0;
            if (j < Hn) {
                if (k < Hn) v = f2bf(wrow[k]);
                else if (mat == 0 && k == 100) v = f2bf(u1);
                else if (mat == 0 && k == 101) v = f2bf(wc1);
                else if (mat == 1 && k == 101) v = f2bf(bih2[row] + bhh2[row]);
            }
            hh[jj] = v;
        }
        u.x = (unsigned)hh[0] | ((unsigned)hh[1] << 16);
        u.y = (unsigned)hh[2] | ((unsigned)hh[3] << 16);
        u.z = (unsigned)hh[4] | ((unsigned)hh[5] << 16);
        u.w = (unsigned)hh[6] | ((unsigned)hh[7] << 16);
        ((uint4*)((char*)ws + mat * FRAG_BYTES))[f * 64 + lane] = u;
    } else {
        int t = gid - 3 * NFRAG * 64;           // 0..1791
        int f = t >> 6;                         // 0..27 = ps*4 + kt
        int ps = f >> 2, kt = f & 3;
        int kbase = kt * 32 + q * 8;
#pragma unroll
        for (int jj = 0; jj < 8; ++jj) {
            int k = kbase + jj;
            unsigned short v = 0;
            if (l < Pn) {
                if (k < Hn) v = f2bf(W2[l * (Pn * Hn) + ps * Hn + k]);
                else if (k == 101 && ps == 6) v = f2bf(b2[l]);
            }
            hh[jj] = v;
        }
        u.x = (unsigned)hh[0] | ((unsigned)hh[1] << 16);
        u.y = (unsigned)hh[2] | ((unsigned)hh[3] << 16);
        u.z = (unsigned)hh[4] | ((unsigned)hh[5] << 16);
        u.w = (unsigned)hh[6] | ((unsigned)hh[7] << 16);
        ((uint4*)((char*)ws + WS_W2_OFF))[f * 64 + lane] = u;
    }
}

__global__ __launch_bounds__(512, 4) void lstm_fused(
    const float* __restrict__ x,     // (T,B)
    const float* __restrict__ ws,    // packed frags (+folds)
    float* __restrict__ out)         // (B,7)
{
    extern __shared__ unsigned short sm[];
    unsigned short* hb0 = sm;                   // h double buffer [row ROWS][k KP]
    unsigned short* hb1 = sm + HBUF_USH;
    unsigned short* g2 = sm + 2 * HBUF_USH;     // gin2 bf16 [n 512][row RP]
    unsigned short* xlb = sm + XL_USH_OFF;      // x slice as bf16 [t 30][row 32]

    const int tid = threadIdx.x;
    const int wave = tid >> 6, lane = tid & 63;
    const int l = lane & 15, q = lane >> 4;
    const int jcol = wave * 16 + l;             // this wave's unit column (0..127)
    const int rowbase = blockIdx.x * ROWS;
    const bool active = (wave < 7);             // wave 7: padding units; does FC2 in phase 2

    for (int i = tid; i < 2 * HBUF_USH; i += 512) sm[i] = 0;
    for (int i = tid; i < Tn * ROWS; i += 512)
        xlb[i] = f2bf_i(x[(i >> 5) * Bn + rowbase + (i & 31)]);
    __syncthreads();   // zeroing + x staging done before seeding
    if (tid < ROWS) {
        hb0[tid * KP + 100] = xlb[tid];                 // x_0 in K slot 100
        hb0[tid * KP + 101] = (unsigned short)0x3F80;   // 1.0 in K slot 101
    }

    // this wave's 16 Whh1 B-frags -> registers (held for all 30 steps; AGPR-resident)
    short8 bf[4][4];   // [G][kt]
    floatx4 cst[RGn];  // cell state per rg, rows 4q+r, unit jcol
    const floatx4 zro = (floatx4){0.f, 0.f, 0.f, 0.f};
    if (active) {
        const short8* fr = (const short8*)ws;
#pragma unroll
        for (int G = 0; G < 4; ++G)
#pragma unroll
            for (int kt = 0; kt < 4; ++kt)
                bf[G][kt] = fr[((((G << 3) | wave) << 2) + kt) * 64 + lane];
#pragma unroll
        for (int rg = 0; rg < RGn; ++rg) cst[rg] = zro;
    }
    __syncthreads();   // h buffers ready (zero + seed)

    // ---- Phase 1: LSTM1, 30 steps, 1 barrier/step ----
    for (int t = 0; t < Tn; ++t) {
        const unsigned short* hc = (t & 1) ? hb1 : hb0;
        unsigned short* hn = (t & 1) ? hb0 : hb1;
        if (active) {
            int tn = (t < Tn - 1) ? t + 1 : t;
#pragma unroll
            for (int rg = 0; rg < RGn; ++rg) {
                short8 af[4];   // A[m=l][k=kt*32+q*8+j], rows rg*16+m
#pragma unroll
                for (int kt = 0; kt < 4; ++kt)
                    af[kt] = *(const short8*)(hc + (rg * 16 + l) * KP + kt * 32 + q * 8);
                floatx4 acc[4];
#pragma unroll
                for (int G = 0; G < 4; ++G)
                    acc[G] = __builtin_amdgcn_mfma_f32_16x16x32_bf16(af[0], bf[G][0], zro, 0, 0, 0);
#pragma unroll
                for (int kt = 1; kt < 4; ++kt)
#pragma unroll
                    for (int G = 0; G < 4; ++G)
                        acc[G] = __builtin_amdgcn_mfma_f32_16x16x32_bf16(
                            af[kt], bf[G][kt], acc[G], 0, 0, 0);
                ushortx4 xn4;
                if (wave == 6)
                    xn4 = *(const ushortx4*)(xlb + tn * ROWS + rg * 16 + 4 * q);
#pragma unroll
                for (int r = 0; r < 4; ++r) {
                    float iv = sig_(acc[0][r]);
                    float fv = sig_(acc[1][r]);
                    float gv = tanh_(acc[2][r]);
                    float ov = sig_(acc[3][r]);
                    float cc = fv * cst[rg][r] + iv * gv;
                    cst[rg][r] = cc;
                    unsigned short us = f2bf_i(ov * tanh_(cc));
                    if (wave == 6)   // cols 100..111 are padding: carry x_{t+1} and 1.0
                        us = (l < 4) ? us
                           : (l == 4) ? (unsigned short)xn4[r]
                           : (l == 5) ? (unsigned short)0x3F80 : (unsigned short)0;
                    hn[(rg * 16 + 4 * q + r) * KP + jcol] = us;
                }
            }
        }
        __syncthreads();
    }

    // ---- Wih2 frags; gin2 = (bih2+bhh2 fold) + last·Wih2^T parked in LDS (wave-private n) ----
    if (active) {
        const short8* fr = (const short8*)((const char*)ws + FRAG_BYTES);
#pragma unroll
        for (int G = 0; G < 4; ++G)
#pragma unroll
            for (int kt = 0; kt < 4; ++kt)
                bf[G][kt] = fr[((((G << 3) | wave) << 2) + kt) * 64 + lane];
        const unsigned short* hl = hb0;   // last = h after t=29 (t=29 odd -> hn was hb0)
#pragma unroll
        for (int rg = 0; rg < RGn; ++rg) {
            short8 af[4];
#pragma unroll
            for (int kt = 0; kt < 4; ++kt)
                af[kt] = *(const short8*)(hl + (rg * 16 + l) * KP + kt * 32 + q * 8);
            floatx4 acc[4];
#pragma unroll
            for (int G = 0; G < 4; ++G)
                acc[G] = __builtin_amdgcn_mfma_f32_16x16x32_bf16(af[0], bf[G][0], zro, 0, 0, 0);
#pragma unroll
            for (int kt = 1; kt < 4; ++kt)
#pragma unroll
                for (int G = 0; G < 4; ++G)
                    acc[G] = __builtin_amdgcn_mfma_f32_16x16x32_bf16(
                        af[kt], bf[G][kt], acc[G], 0, 0, 0);
#pragma unroll
            for (int G = 0; G < 4; ++G) {
                int n = G * 128 + jcol;
                uint2 pk;
                pk.x = (unsigned)f2bf_i(acc[G][0]) | ((unsigned)f2bf_i(acc[G][1]) << 16);
                pk.y = (unsigned)f2bf_i(acc[G][2]) | ((unsigned)f2bf_i(acc[G][3]) << 16);
                *(uint2*)(g2 + n * RP + rg * 16 + 4 * q) = pk;   // same wave reads it back
            }
        }
        // ---- Whh2 frags ----
        const short8* fr2 = (const short8*)((const char*)ws + 2 * FRAG_BYTES);
#pragma unroll
        for (int G = 0; G < 4; ++G)
#pragma unroll
            for (int kt = 0; kt < 4; ++kt)
                bf[G][kt] = fr2[((((G << 3) | wave) << 2) + kt) * 64 + lane];
    }

    // ---- Phase 2: LSTM2, 7 steps; FC2 runs on the otherwise-idle wave 7 ----
    const short8* w2fr = (const short8*)((const char*)ws + WS_W2_OFF);
    floatx4 yfc[RGn];
    if (wave == 7) {
#pragma unroll
        for (int rg = 0; rg < RGn; ++rg) yfc[rg] = zro;
    }

    for (int ps = 0; ps < Pn; ++ps) {
        int t = Tn + ps;
        const unsigned short* hc = (t & 1) ? hb1 : hb0;
        unsigned short* hn = (t & 1) ? hb0 : hb1;
        if (wave == 7) {
            if (ps >= 1) {   // hc holds h2 of step ps-1
                short8 w2f[4];
#pragma unroll
                for (int kt = 0; kt < 4; ++kt)
                    w2f[kt] = w2fr[((ps - 1) * 4 + kt) * 64 + lane];
#pragma unroll
                for (int rg = 0; rg < RGn; ++rg) {
                    short8 af2[4];
#pragma unroll
                    for (int kt = 0; kt < 4; ++kt)
                        af2[kt] = *(const short8*)(hc + (rg * 16 + l) * KP + kt * 32 + q * 8);
#pragma unroll
                    for (int kt = 0; kt < 4; ++kt)
                        yfc[rg] = __builtin_amdgcn_mfma_f32_16x16x32_bf16(
                            af2[kt], w2f[kt], yfc[rg], 0, 0, 0);
                }
            }
        } else {
#pragma unroll
            for (int rg = 0; rg < RGn; ++rg) {
                short8 af[4];
#pragma unroll
                for (int kt = 0; kt < 4; ++kt)
                    af[kt] = *(const short8*)(hc + (rg * 16 + l) * KP + kt * 32 + q * 8);
                floatx4 acc[4];
#pragma unroll
                for (int G = 0; G < 4; ++G) {
                    int n = G * 128 + jcol;
                    uint2 pk = *(const uint2*)(g2 + n * RP + rg * 16 + 4 * q);
                    acc[G][0] = __uint_as_float(pk.x << 16);
                    acc[G][1] = __uint_as_float(pk.x & 0xFFFF0000u);
                    acc[G][2] = __uint_as_float(pk.y << 16);
                    acc[G][3] = __uint_as_float(pk.y & 0xFFFF0000u);
                }
#pragma unroll
                for (int kt = 0; kt < 4; ++kt)
#pragma unroll
                    for (int G = 0; G < 4; ++G)
                        acc[G] = __builtin_amdgcn_mfma_f32_16x16x32_bf16(
                            af[kt], bf[G][kt], acc[G], 0, 0, 0);
#pragma unroll
                for (int r = 0; r < 4; ++r) {
                    float iv = sig_(acc[0][r]);
                    float fv = sig_(acc[1][r]);
                    float gv = tanh_(acc[2][r]);
                    float ov = sig_(acc[3][r]);
                    float cc = fv * cst[rg][r] + iv * gv;
                    cst[rg][r] = cc;
                    unsigned short us = f2bf_i(ov * tanh_(cc));
                    if (wave == 6)   // phase 2: keep 1.0 at col 101 (b2 fold), zero pads
                        us = (l < 4) ? us
                           : (l == 5) ? (unsigned short)0x3F80 : (unsigned short)0;
                    hn[(rg * 16 + 4 * q + r) * KP + jcol] = us;   // ps=6 too (final FC2)
                }
            }
        }
        __syncthreads();
    }

    // ---- final FC2 for h2 of ps=6 (t=36 even -> hn=hb1); b2 folded into ps=6 frag k=101 ----
    if (wave == 7) {
        short8 w2f[4];
#pragma unroll
        for (int kt = 0; kt < 4; ++kt)
            w2f[kt] = w2fr[(6 * 4 + kt) * 64 + lane];
#pragma unroll
        for (int rg = 0; rg < RGn; ++rg) {
            short8 af2[4];
#pragma unroll
            for (int kt = 0; kt < 4; ++kt)
                af2[kt] = *(const short8*)(hb1 + (rg * 16 + l) * KP + kt * 32 + q * 8);
#pragma unroll
            for (int kt = 0; kt < 4; ++kt)
                yfc[rg] = __builtin_amdgcn_mfma_f32_16x16x32_bf16(
                    af2[kt], w2f[kt], yfc[rg], 0, 0, 0);
            if (l < Pn) {
#pragma unroll
                for (int r = 0; r < 4; ++r)
                    out[(rowbase + rg * 16 + 4 * q + r) * Pn + l] = sig_(yfc[rg][r]);
            }
        }
    }
}

extern "C" void kernel_launch(void* const* d_in, const int* in_sizes, int n_in,
                              void* d_out, int out_size, void* d_ws, size_t ws_size,
                              hipStream_t stream) {
    const float* x    = (const float*)d_in[0];
    const float* W1   = (const float*)d_in[1];
    const float* b1   = (const float*)d_in[2];
    const float* Wih1 = (const float*)d_in[3];
    const float* Whh1 = (const float*)d_in[4];
    const float* bih1 = (const float*)d_in[5];
    const float* bhh1 = (const float*)d_in[6];
    const float* Wih2 = (const float*)d_in[7];
    const float* Whh2 = (const float*)d_in[8];
    const float* bih2 = (const float*)d_in[9];
    const float* bhh2 = (const float*)d_in[10];
    const float* W2   = (const float*)d_in[11];
    const float* b2   = (const float*)d_in[12];
    float* out = (float*)d_out;
    float* ws  = (float*)d_ws;

    (void)hipFuncSetAttribute((const void*)lstm_fused,
                              hipFuncAttributeMaxDynamicSharedMemorySize, SMEM_BYTES);

    setup_kernel<<<PACK_BLOCKS, 256, 0, stream>>>(W1, b1, Wih1, bih1, bhh1,
                                                  bih2, bhh2, Whh1, Wih2, Whh2, W2, b2, ws);
    lstm_fused<<<Bn / ROWS, 512, SMEM_BYTES, stream>>>(x, ws, out);
}

// Round 5
// 199.587 us; speedup vs baseline: 1.1229x; 1.1229x over previous
//
#include <hip/hip_runtime.h>
#include <math.h>

// Problem constants
#define Tn 30
#define Bn 16384
#define Hn 100
#define Pn 7

// Tiling: gates padded 100->128 units => N=512 (32 n-tiles); K padded 100->128 (4 k-tiles of 32).
// K slots 100/101 carry the FC1 fold: A[k=100]=x_t(row), A[k=101]=1.0 (maintained by wave 6,
// whose unit columns 100..111 are padding); Whh1 B rows 100/101 hold u1[j]/wc1[j].
// 32 rows/block (grid 512), 8 waves; wave w owns units [16w,16w+16); wave 7 idle in phase 1,
// runs FC2 in phase 2. __launch_bounds__(512,4): 128 total regs/wave, HW-split 64 arch + 64 acc
// (bf frags live in AGPR) => 2 blocks/CU = 4 waves/SIMD.
// Round-5: two-gate phasing (i,g -> pc; then f,o -> c,h) cuts peak acc liveness 16->12 so the
// arch set fits the 64-reg cap (round-3/4 spilled ~13-17 MB scratch; that was the residual tax).
#define ROWS 32           // rows per block
#define RGn 2             // row-groups of 16
#define KP 136            // h row pitch (ushorts); 272B -> 16B-aligned A-frag reads
#define RP 36             // gin2 row pitch (ushorts): 32 rows + 4 pad
#define NFRAG 128         // B-frags per matrix (32 nt x 4 kt)
#define FRAG_BYTES (NFRAG * 64 * 16)   // 131072 per matrix
#define WS_W2_OFF (3 * FRAG_BYTES)     // 28 W2 frags (7 ps x 4 kt)
#define HBUF_USH (ROWS * KP)           // 4352
#define G2_USH (512 * RP)              // 18432
#define XL_USH_OFF (2 * HBUF_USH + G2_USH)            // 27136 ushorts
#define SMEM_BYTES (XL_USH_OFF * 2 + Tn * ROWS * 4)   // 54272 + 3840 = 58112

#define PACK_BLOCKS 103   // (3*128*64 + 28*64)/256 exactly

typedef __attribute__((ext_vector_type(8))) short short8;   // 8 bf16 (4 VGPRs)
typedef __attribute__((ext_vector_type(4))) float floatx4;  // MFMA C/D

__device__ __forceinline__ float rcp_(float v) { return __builtin_amdgcn_rcpf(v); }
__device__ __forceinline__ float sig_(float v) { return rcp_(1.0f + __expf(-v)); }
__device__ __forceinline__ float tanh_(float v) { return 1.0f - 2.0f * rcp_(__expf(2.0f * v) + 1.0f); }
__device__ __forceinline__ unsigned short f2bf(float v) {
    unsigned int u = __float_as_uint(v);
    return (unsigned short)((u + 0x7FFFu + ((u >> 16) & 1u)) >> 16);   // RNE
}

// Pack the 3 recurrent matrices (400x100) into bf16 B-frag layout (gates padded to 128 units),
// with the bias/FC1 folds in padded K rows:
//   mat 0 (Whh1): k=100 -> u1[j] = Wih1[j,:]·W1 ; k=101 -> wc1[j] = Wih1[j,:]·b1 + bih1[j] + bhh1[j]
//   mat 1 (Wih2): k=101 -> bih2[j] + bhh2[j]
//   W2 frags:     k=101 && ps==6 -> b2[p]   (A k=101 is 1.0 every step; add bias exactly once)
// B[k][n]: n = lane&15, k = (lane>>4)*8 + jj  (16x16x32 bf16 B mapping, HW-verified).
__global__ void setup_kernel(const float* __restrict__ W1,
                             const float* __restrict__ b1,
                             const float* __restrict__ Wih1,
                             const float* __restrict__ bih1,
                             const float* __restrict__ bhh1,
                             const float* __restrict__ bih2,
                             const float* __restrict__ bhh2,
                             const float* __restrict__ Whh1,
                             const float* __restrict__ Wih2,
                             const float* __restrict__ Whh2,
                             const float* __restrict__ W2,
                             const float* __restrict__ b2,
                             float* __restrict__ ws) {
    int gid = blockIdx.x * 256 + threadIdx.x;   // 3*128*64 + 28*64 = 26368
    int lane = gid & 63;
    int l = lane & 15, q = lane >> 4;
    unsigned short hh[8];
    uint4 u;
    if (gid < 3 * NFRAG * 64) {
        int mat = gid / (NFRAG * 64);
        int f = (gid % (NFRAG * 64)) >> 6;
        int nt = f >> 2, kt = f & 3;
        int G = nt >> 3, ag = nt & 7;
        int j = ag * 16 + l;                    // unit within gate
        int row = G * Hn + (j < Hn ? j : 0);    // row of the 400-row weight matrices
        const float* W = (mat == 0) ? Whh1 : (mat == 1) ? Wih2 : Whh2;
        const float* wrow = W + row * Hn;
        float u1 = 0.f, wc1 = 0.f;
        if (mat == 0 && kt == 3 && q == 0 && j < Hn) {   // lanes producing k=100/101
            for (int k = 0; k < Hn; ++k) {
                float a = Wih1[row * Hn + k];
                u1 += a * W1[k];
                wc1 += a * b1[k];
            }
            wc1 += bih1[row] + bhh1[row];
        }
        int kbase = kt * 32 + q * 8;
#pragma unroll
        for (int jj = 0; jj < 8; ++jj) {
            int k = kbase + jj;
            unsigned short v = 0;
            if (j < Hn) {
                if (k < Hn) v = f2bf(wrow[k]);
                else if (mat == 0 && k == 100) v = f2bf(u1);
                else if (mat == 0 && k == 101) v = f2bf(wc1);
                else if (mat == 1 && k == 101) v = f2bf(bih2[row] + bhh2[row]);
            }
            hh[jj] = v;
        }
        u.x = (unsigned)hh[0] | ((unsigned)hh[1] << 16);
        u.y = (unsigned)hh[2] | ((unsigned)hh[3] << 16);
        u.z = (unsigned)hh[4] | ((unsigned)hh[5] << 16);
        u.w = (unsigned)hh[6] | ((unsigned)hh[7] << 16);
        ((uint4*)((char*)ws + mat * FRAG_BYTES))[f * 64 + lane] = u;
    } else {
        int t = gid - 3 * NFRAG * 64;           // 0..1791
        int f = t >> 6;                         // 0..27 = ps*4 + kt
        int ps = f >> 2, kt = f & 3;
        int kbase = kt * 32 + q * 8;
#pragma unroll
        for (int jj = 0; jj < 8; ++jj) {
            int k = kbase + jj;
            unsigned short v = 0;
            if (l < Pn) {
                if (k < Hn) v = f2bf(W2[l * (Pn * Hn) + ps * Hn + k]);
                else if (k == 101 && ps == 6) v = f2bf(b2[l]);
            }
            hh[jj] = v;
        }
        u.x = (unsigned)hh[0] | ((unsigned)hh[1] << 16);
        u.y = (unsigned)hh[2] | ((unsigned)hh[3] << 16);
        u.z = (unsigned)hh[4] | ((unsigned)hh[5] << 16);
        u.w = (unsigned)hh[6] | ((unsigned)hh[7] << 16);
        ((uint4*)((char*)ws + WS_W2_OFF))[f * 64 + lane] = u;
    }
}

__global__ __launch_bounds__(512, 4) void lstm_fused(
    const float* __restrict__ x,     // (T,B)
    const float* __restrict__ ws,    // packed frags (+folds)
    float* __restrict__ out)         // (B,7)
{
    extern __shared__ unsigned short sm[];
    unsigned short* hb0 = sm;                   // h double buffer [row ROWS][k KP]
    unsigned short* hb1 = sm + HBUF_USH;
    unsigned short* g2 = sm + 2 * HBUF_USH;     // gin2 bf16 [n 512][row RP]
    float* xl = (float*)(sm + XL_USH_OFF);      // x slice [t 30][row 32]

    const int tid = threadIdx.x;
    const int wave = tid >> 6, lane = tid & 63;
    const int l = lane & 15, q = lane >> 4;
    const int jcol = wave * 16 + l;             // this wave's unit column (0..127)
    const int rowbase = blockIdx.x * ROWS;
    const bool active = (wave < 7);             // wave 7: padding units; does FC2 in phase 2

    for (int i = tid; i < 2 * HBUF_USH; i += 512) sm[i] = 0;
    for (int i = tid; i < Tn * ROWS; i += 512)
        xl[i] = x[(i >> 5) * Bn + rowbase + (i & 31)];
    __syncthreads();   // zeroing + x staging done before seeding
    if (tid < ROWS) {
        hb0[tid * KP + 100] = f2bf(x[rowbase + tid]);   // x_0 in K slot 100
        hb0[tid * KP + 101] = (unsigned short)0x3F80;   // 1.0 in K slot 101
    }

    // this wave's 16 Whh1 B-frags -> registers (held for all 30 steps; AGPR-resident)
    short8 bf[4][4];   // [G][kt]
    floatx4 cst[RGn];  // cell state per rg, rows 4q+r, unit jcol
    const floatx4 zro = (floatx4){0.f, 0.f, 0.f, 0.f};
    if (active) {
        const short8* fr = (const short8*)ws;
#pragma unroll
        for (int G = 0; G < 4; ++G)
#pragma unroll
            for (int kt = 0; kt < 4; ++kt)
                bf[G][kt] = fr[((((G << 3) | wave) << 2) + kt) * 64 + lane];
#pragma unroll
        for (int rg = 0; rg < RGn; ++rg) cst[rg] = zro;
    }
    __syncthreads();   // h buffers ready (zero + seed)

    // ---- Phase 1: LSTM1, 30 steps, 1 barrier/step ----
    for (int t = 0; t < Tn; ++t) {
        const unsigned short* hc = (t & 1) ? hb1 : hb0;
        unsigned short* hn = (t & 1) ? hb0 : hb1;
        if (active) {
            int tn = (t < Tn - 1) ? t + 1 : t;
#pragma unroll
            for (int rg = 0; rg < RGn; ++rg) {
                short8 af[4];   // A[m=l][k=kt*32+q*8+j], rows rg*16+m
#pragma unroll
                for (int kt = 0; kt < 4; ++kt)
                    af[kt] = *(const short8*)(hc + (rg * 16 + l) * KP + kt * 32 + q * 8);
                // ---- gate phase A: i (G0), g (G2) -> pc = sig(i)*tanh(g) ----
                floatx4 a0, a1;
                a0 = __builtin_amdgcn_mfma_f32_16x16x32_bf16(af[0], bf[0][0], zro, 0, 0, 0);
                a1 = __builtin_amdgcn_mfma_f32_16x16x32_bf16(af[0], bf[2][0], zro, 0, 0, 0);
#pragma unroll
                for (int kt = 1; kt < 4; ++kt) {
                    a0 = __builtin_amdgcn_mfma_f32_16x16x32_bf16(af[kt], bf[0][kt], a0, 0, 0, 0);
                    a1 = __builtin_amdgcn_mfma_f32_16x16x32_bf16(af[kt], bf[2][kt], a1, 0, 0, 0);
                }
                float pc[4];
#pragma unroll
                for (int r = 0; r < 4; ++r)
                    pc[r] = sig_(a0[r]) * tanh_(a1[r]);
                // ---- gate phase B: f (G1), o (G3) -> c, h ----
                a0 = __builtin_amdgcn_mfma_f32_16x16x32_bf16(af[0], bf[1][0], zro, 0, 0, 0);
                a1 = __builtin_amdgcn_mfma_f32_16x16x32_bf16(af[0], bf[3][0], zro, 0, 0, 0);
#pragma unroll
                for (int kt = 1; kt < 4; ++kt) {
                    a0 = __builtin_amdgcn_mfma_f32_16x16x32_bf16(af[kt], bf[1][kt], a0, 0, 0, 0);
                    a1 = __builtin_amdgcn_mfma_f32_16x16x32_bf16(af[kt], bf[3][kt], a1, 0, 0, 0);
                }
                float4 xn4;
                if (wave == 6)
                    xn4 = *(const float4*)(xl + tn * ROWS + rg * 16 + 4 * q);
#pragma unroll
                for (int r = 0; r < 4; ++r) {
                    float cc = sig_(a0[r]) * cst[rg][r] + pc[r];
                    cst[rg][r] = cc;
                    unsigned short us = f2bf(sig_(a1[r]) * tanh_(cc));
                    if (wave == 6)   // cols 100..111 are padding: carry x_{t+1} and 1.0
                        us = (l < 4) ? us
                           : (l == 4) ? f2bf(xn4[r])
                           : (l == 5) ? (unsigned short)0x3F80 : (unsigned short)0;
                    hn[(rg * 16 + 4 * q + r) * KP + jcol] = us;
                }
            }
        }
        __syncthreads();
    }

    // ---- Wih2 frags; gin2 = (bih2+bhh2 fold) + last·Wih2^T parked in LDS (wave-private n) ----
    if (active) {
        const short8* fr = (const short8*)((const char*)ws + FRAG_BYTES);
#pragma unroll
        for (int G = 0; G < 4; ++G)
#pragma unroll
            for (int kt = 0; kt < 4; ++kt)
                bf[G][kt] = fr[((((G << 3) | wave) << 2) + kt) * 64 + lane];
        const unsigned short* hl = hb0;   // last = h after t=29 (t=29 odd -> hn was hb0)
#pragma unroll
        for (int rg = 0; rg < RGn; ++rg) {
            short8 af[4];
#pragma unroll
            for (int kt = 0; kt < 4; ++kt)
                af[kt] = *(const short8*)(hl + (rg * 16 + l) * KP + kt * 32 + q * 8);
            floatx4 acc[4];
#pragma unroll
            for (int G = 0; G < 4; ++G)
                acc[G] = __builtin_amdgcn_mfma_f32_16x16x32_bf16(af[0], bf[G][0], zro, 0, 0, 0);
#pragma unroll
            for (int kt = 1; kt < 4; ++kt)
#pragma unroll
                for (int G = 0; G < 4; ++G)
                    acc[G] = __builtin_amdgcn_mfma_f32_16x16x32_bf16(
                        af[kt], bf[G][kt], acc[G], 0, 0, 0);
#pragma unroll
            for (int G = 0; G < 4; ++G) {
                int n = G * 128 + jcol;
                uint2 pk;
                pk.x = (unsigned)f2bf(acc[G][0]) | ((unsigned)f2bf(acc[G][1]) << 16);
                pk.y = (unsigned)f2bf(acc[G][2]) | ((unsigned)f2bf(acc[G][3]) << 16);
                *(uint2*)(g2 + n * RP + rg * 16 + 4 * q) = pk;   // same wave reads it back
            }
        }
        // ---- Whh2 frags ----
        const short8* fr2 = (const short8*)((const char*)ws + 2 * FRAG_BYTES);
#pragma unroll
        for (int G = 0; G < 4; ++G)
#pragma unroll
            for (int kt = 0; kt < 4; ++kt)
                bf[G][kt] = fr2[((((G << 3) | wave) << 2) + kt) * 64 + lane];
    }

    // ---- Phase 2: LSTM2, 7 steps; FC2 runs on the otherwise-idle wave 7 ----
    const short8* w2fr = (const short8*)((const char*)ws + WS_W2_OFF);
    floatx4 yfc[RGn];
    if (wave == 7) {
#pragma unroll
        for (int rg = 0; rg < RGn; ++rg) yfc[rg] = zro;
    }

    for (int ps = 0; ps < Pn; ++ps) {
        int t = Tn + ps;
        const unsigned short* hc = (t & 1) ? hb1 : hb0;
        unsigned short* hn = (t & 1) ? hb0 : hb1;
        if (wave == 7) {
            if (ps >= 1) {   // hc holds h2 of step ps-1
                short8 w2f[4];
#pragma unroll
                for (int kt = 0; kt < 4; ++kt)
                    w2f[kt] = w2fr[((ps - 1) * 4 + kt) * 64 + lane];
#pragma unroll
                for (int rg = 0; rg < RGn; ++rg) {
                    short8 af2[4];
#pragma unroll
                    for (int kt = 0; kt < 4; ++kt)
                        af2[kt] = *(const short8*)(hc + (rg * 16 + l) * KP + kt * 32 + q * 8);
#pragma unroll
                    for (int kt = 0; kt < 4; ++kt)
                        yfc[rg] = __builtin_amdgcn_mfma_f32_16x16x32_bf16(
                            af2[kt], w2f[kt], yfc[rg], 0, 0, 0);
                }
            }
        } else {
#pragma unroll
            for (int rg = 0; rg < RGn; ++rg) {
                short8 af[4];
#pragma unroll
                for (int kt = 0; kt < 4; ++kt)
                    af[kt] = *(const short8*)(hc + (rg * 16 + l) * KP + kt * 32 + q * 8);
                // ---- gate phase A: i (G0), g (G2) ----
                floatx4 a0, a1;
                {
                    int n0 = 0 * 128 + jcol, n1 = 2 * 128 + jcol;
                    uint2 p0 = *(const uint2*)(g2 + n0 * RP + rg * 16 + 4 * q);
                    uint2 p1 = *(const uint2*)(g2 + n1 * RP + rg * 16 + 4 * q);
                    a0[0] = __uint_as_float(p0.x << 16);
                    a0[1] = __uint_as_float(p0.x & 0xFFFF0000u);
                    a0[2] = __uint_as_float(p0.y << 16);
                    a0[3] = __uint_as_float(p0.y & 0xFFFF0000u);
                    a1[0] = __uint_as_float(p1.x << 16);
                    a1[1] = __uint_as_float(p1.x & 0xFFFF0000u);
                    a1[2] = __uint_as_float(p1.y << 16);
                    a1[3] = __uint_as_float(p1.y & 0xFFFF0000u);
                }
#pragma unroll
                for (int kt = 0; kt < 4; ++kt) {
                    a0 = __builtin_amdgcn_mfma_f32_16x16x32_bf16(af[kt], bf[0][kt], a0, 0, 0, 0);
                    a1 = __builtin_amdgcn_mfma_f32_16x16x32_bf16(af[kt], bf[2][kt], a1, 0, 0, 0);
                }
                float pc[4];
#pragma unroll
                for (int r = 0; r < 4; ++r)
                    pc[r] = sig_(a0[r]) * tanh_(a1[r]);
                // ---- gate phase B: f (G1), o (G3) ----
                {
                    int n0 = 1 * 128 + jcol, n1 = 3 * 128 + jcol;
                    uint2 p0 = *(const uint2*)(g2 + n0 * RP + rg * 16 + 4 * q);
                    uint2 p1 = *(const uint2*)(g2 + n1 * RP + rg * 16 + 4 * q);
                    a0[0] = __uint_as_float(p0.x << 16);
                    a0[1] = __uint_as_float(p0.x & 0xFFFF0000u);
                    a0[2] = __uint_as_float(p0.y << 16);
                    a0[3] = __uint_as_float(p0.y & 0xFFFF0000u);
                    a1[0] = __uint_as_float(p1.x << 16);
                    a1[1] = __uint_as_float(p1.x & 0xFFFF0000u);
                    a1[2] = __uint_as_float(p1.y << 16);
                    a1[3] = __uint_as_float(p1.y & 0xFFFF0000u);
                }
#pragma unroll
                for (int kt = 0; kt < 4; ++kt) {
                    a0 = __builtin_amdgcn_mfma_f32_16x16x32_bf16(af[kt], bf[1][kt], a0, 0, 0, 0);
                    a1 = __builtin_amdgcn_mfma_f32_16x16x32_bf16(af[kt], bf[3][kt], a1, 0, 0, 0);
                }
#pragma unroll
                for (int r = 0; r < 4; ++r) {
                    float cc = sig_(a0[r]) * cst[rg][r] + pc[r];
                    cst[rg][r] = cc;
                    unsigned short us = f2bf(sig_(a1[r]) * tanh_(cc));
                    if (wave == 6)   // phase 2: keep 1.0 at col 101 (b2 fold), zero pads
                        us = (l < 4) ? us
                           : (l == 5) ? (unsigned short)0x3F80 : (unsigned short)0;
                    hn[(rg * 16 + 4 * q + r) * KP + jcol] = us;   // ps=6 too (final FC2)
                }
            }
        }
        __syncthreads();
    }

    // ---- final FC2 for h2 of ps=6 (t=36 even -> hn=hb1); b2 folded into ps=6 frag k=101 ----
    if (wave == 7) {
        short8 w2f[4];
#pragma unroll
        for (int kt = 0; kt < 4; ++kt)
            w2f[kt] = w2fr[(6 * 4 + kt) * 64 + lane];
#pragma unroll
        for (int rg = 0; rg < RGn; ++rg) {
            short8 af2[4];
#pragma unroll
            for (int kt = 0; kt < 4; ++kt)
                af2[kt] = *(const short8*)(hb1 + (rg * 16 + l) * KP + kt * 32 + q * 8);
#pragma unroll
            for (int kt = 0; kt < 4; ++kt)
                yfc[rg] = __builtin_amdgcn_mfma_f32_16x16x32_bf16(
                    af2[kt], w2f[kt], yfc[rg], 0, 0, 0);
            if (l < Pn) {
#pragma unroll
                for (int r = 0; r < 4; ++r)
                    out[(rowbase + rg * 16 + 4 * q + r) * Pn + l] = sig_(yfc[rg][r]);
            }
        }
    }
}

extern "C" void kernel_launch(void* const* d_in, const int* in_sizes, int n_in,
                              void* d_out, int out_size, void* d_ws, size_t ws_size,
                              hipStream_t stream) {
    const float* x    = (const float*)d_in[0];
    const float* W1   = (const float*)d_in[1];
    const float* b1   = (const float*)d_in[2];
    const float* Wih1 = (const float*)d_in[3];
    const float* Whh1 = (const float*)d_in[4];
    const float* bih1 = (const float*)d_in[5];
    const float* bhh1 = (const float*)d_in[6];
    const float* Wih2 = (const float*)d_in[7];
    const float* Whh2 = (const float*)d_in[8];
    const float* bih2 = (const float*)d_in[9];
    const float* bhh2 = (const float*)d_in[10];
    const float* W2   = (const float*)d_in[11];
    const float* b2   = (const float*)d_in[12];
    float* out = (float*)d_out;
    float* ws  = (float*)d_ws;

    (void)hipFuncSetAttribute((const void*)lstm_fused,
                              hipFuncAttributeMaxDynamicSharedMemorySize, SMEM_BYTES);

    setup_kernel<<<PACK_BLOCKS, 256, 0, stream>>>(W1, b1, Wih1, bih1, bhh1,
                                                  bih2, bhh2, Whh1, Wih2, Whh2, W2, b2, ws);
    lstm_fused<<<Bn / ROWS, 512, SMEM_BYTES, stream>>>(x, ws, out);
}

// Round 6
// 198.671 us; speedup vs baseline: 1.1281x; 1.0046x over previous
//
#include <hip/hip_runtime.h>
#include <math.h>

// Problem constants
#define Tn 30
#define Bn 16384
#define Hn 100
#define Pn 7

// Tiling: gates padded 100->128 units => N=512 (32 n-tiles); K padded 100->128 (4 k-tiles of 32).
// K slots 100/101 carry the FC1 fold: A[k=100]=x_t(row), A[k=101]=1.0; Whh1 B rows 100/101 hold
// u1[j]/wc1[j]; Wih2 row 101 holds bih2+bhh2; W2(ps=6) row 101 holds b2.
// 32 rows/block (grid 512), 8 waves; wave w<7 owns units [16w,16w+16) (jcol>=100 lanes are pad,
// stores predicated jcol<Hn). Wave 7: maintains K-slots 100/101 of hn each phase-1 step (it was
// idle), runs FC2 in phase 2. __launch_bounds__(512,4): 128 total regs/wave, HW-split 64 arch +
// 64 acc (bf frags in AGPR) => 2 blocks/CU = 4 waves/SIMD.
// Round-6: slot maintenance moved off the compute epilogue (kills xn4/cndmask chain) + t-loop
// unrolled x2 (compile-time hc/hn) so the arch set fits the 64-reg cap (rounds 3-5 spilled).
#define ROWS 32           // rows per block
#define RGn 2             // row-groups of 16
#define KP 136            // h row pitch (ushorts); 272B -> 16B-aligned A-frag reads
#define RP 36             // gin2 row pitch (ushorts): 32 rows + 4 pad
#define NFRAG 128         // B-frags per matrix (32 nt x 4 kt)
#define FRAG_BYTES (NFRAG * 64 * 16)   // 131072 per matrix
#define WS_W2_OFF (3 * FRAG_BYTES)     // 28 W2 frags (7 ps x 4 kt)
#define HBUF_USH (ROWS * KP)           // 4352
#define G2_USH (512 * RP)              // 18432
#define XL_USH_OFF (2 * HBUF_USH + G2_USH)            // 27136 ushorts
#define SMEM_BYTES (XL_USH_OFF * 2 + Tn * ROWS * 4)   // 54272 + 3840 = 58112

#define PACK_BLOCKS 103   // (3*128*64 + 28*64)/256 exactly

typedef __attribute__((ext_vector_type(8))) short short8;   // 8 bf16 (4 VGPRs)
typedef __attribute__((ext_vector_type(4))) float floatx4;  // MFMA C/D

__device__ __forceinline__ float rcp_(float v) { return __builtin_amdgcn_rcpf(v); }
__device__ __forceinline__ float sig_(float v) { return rcp_(1.0f + __expf(-v)); }
__device__ __forceinline__ float tanh_(float v) { return 1.0f - 2.0f * rcp_(__expf(2.0f * v) + 1.0f); }
__device__ __forceinline__ unsigned short f2bf(float v) {
    unsigned int u = __float_as_uint(v);
    return (unsigned short)((u + 0x7FFFu + ((u >> 16) & 1u)) >> 16);   // RNE
}

// Pack the 3 recurrent matrices (400x100) into bf16 B-frag layout (gates padded to 128 units),
// with the bias/FC1 folds in padded K rows:
//   mat 0 (Whh1): k=100 -> u1[j] = Wih1[j,:]·W1 ; k=101 -> wc1[j] = Wih1[j,:]·b1 + bih1[j] + bhh1[j]
//   mat 1 (Wih2): k=101 -> bih2[j] + bhh2[j]
//   W2 frags:     k=101 && ps==6 -> b2[p]   (A k=101 is 1.0 every step; add bias exactly once)
// B[k][n]: n = lane&15, k = (lane>>4)*8 + jj  (16x16x32 bf16 B mapping, HW-verified).
__global__ void setup_kernel(const float* __restrict__ W1,
                             const float* __restrict__ b1,
                             const float* __restrict__ Wih1,
                             const float* __restrict__ bih1,
                             const float* __restrict__ bhh1,
                             const float* __restrict__ bih2,
                             const float* __restrict__ bhh2,
                             const float* __restrict__ Whh1,
                             const float* __restrict__ Wih2,
                             const float* __restrict__ Whh2,
                             const float* __restrict__ W2,
                             const float* __restrict__ b2,
                             float* __restrict__ ws) {
    int gid = blockIdx.x * 256 + threadIdx.x;   // 3*128*64 + 28*64 = 26368
    int lane = gid & 63;
    int l = lane & 15, q = lane >> 4;
    unsigned short hh[8];
    uint4 u;
    if (gid < 3 * NFRAG * 64) {
        int mat = gid / (NFRAG * 64);
        int f = (gid % (NFRAG * 64)) >> 6;
        int nt = f >> 2, kt = f & 3;
        int G = nt >> 3, ag = nt & 7;
        int j = ag * 16 + l;                    // unit within gate
        int row = G * Hn + (j < Hn ? j : 0);    // row of the 400-row weight matrices
        const float* W = (mat == 0) ? Whh1 : (mat == 1) ? Wih2 : Whh2;
        const float* wrow = W + row * Hn;
        float u1 = 0.f, wc1 = 0.f;
        if (mat == 0 && kt == 3 && q == 0 && j < Hn) {   // lanes producing k=100/101
            for (int k = 0; k < Hn; ++k) {
                float a = Wih1[row * Hn + k];
                u1 += a * W1[k];
                wc1 += a * b1[k];
            }
            wc1 += bih1[row] + bhh1[row];
        }
        int kbase = kt * 32 + q * 8;
#pragma unroll
        for (int jj = 0; jj < 8; ++jj) {
            int k = kbase + jj;
            unsigned short v = 0;
            if (j < Hn) {
                if (k < Hn) v = f2bf(wrow[k]);
                else if (mat == 0 && k == 100) v = f2bf(u1);
                else if (mat == 0 && k == 101) v = f2bf(wc1);
                else if (mat == 1 && k == 101) v = f2bf(bih2[row] + bhh2[row]);
            }
            hh[jj] = v;
        }
        u.x = (unsigned)hh[0] | ((unsigned)hh[1] << 16);
        u.y = (unsigned)hh[2] | ((unsigned)hh[3] << 16);
        u.z = (unsigned)hh[4] | ((unsigned)hh[5] << 16);
        u.w = (unsigned)hh[6] | ((unsigned)hh[7] << 16);
        ((uint4*)((char*)ws + mat * FRAG_BYTES))[f * 64 + lane] = u;
    } else {
        int t = gid - 3 * NFRAG * 64;           // 0..1791
        int f = t >> 6;                         // 0..27 = ps*4 + kt
        int ps = f >> 2, kt = f & 3;
        int kbase = kt * 32 + q * 8;
#pragma unroll
        for (int jj = 0; jj < 8; ++jj) {
            int k = kbase + jj;
            unsigned short v = 0;
            if (l < Pn) {
                if (k < Hn) v = f2bf(W2[l * (Pn * Hn) + ps * Hn + k]);
                else if (k == 101 && ps == 6) v = f2bf(b2[l]);
            }
            hh[jj] = v;
        }
        u.x = (unsigned)hh[0] | ((unsigned)hh[1] << 16);
        u.y = (unsigned)hh[2] | ((unsigned)hh[3] << 16);
        u.z = (unsigned)hh[4] | ((unsigned)hh[5] << 16);
        u.w = (unsigned)hh[6] | ((unsigned)hh[7] << 16);
        ((uint4*)((char*)ws + WS_W2_OFF))[f * 64 + lane] = u;
    }
}

__global__ __launch_bounds__(512, 4) void lstm_fused(
    const float* __restrict__ x,     // (T,B)
    const float* __restrict__ ws,    // packed frags (+folds)
    float* __restrict__ out)         // (B,7)
{
    extern __shared__ unsigned short sm[];
    unsigned short* hb0 = sm;                   // h double buffer [row ROWS][k KP]
    unsigned short* hb1 = sm + HBUF_USH;
    unsigned short* g2 = sm + 2 * HBUF_USH;     // gin2 bf16 [n 512][row RP]
    float* xl = (float*)(sm + XL_USH_OFF);      // x slice [t 30][row 32]

    const int tid = threadIdx.x;
    const int wave = tid >> 6, lane = tid & 63;
    const int l = lane & 15, q = lane >> 4;
    const int jcol = wave * 16 + l;             // this wave's unit column (0..127)
    const int rowbase = blockIdx.x * ROWS;

    for (int i = tid; i < 2 * HBUF_USH; i += 512) sm[i] = 0;
    for (int i = tid; i < Tn * ROWS; i += 512)
        xl[i] = x[(i >> 5) * Bn + rowbase + (i & 31)];
    __syncthreads();   // zeroing + x staging done before seeding
    if (tid < ROWS) {
        hb0[tid * KP + 100] = f2bf(x[rowbase + tid]);   // x_0 in K slot 100
        hb0[tid * KP + 101] = (unsigned short)0x3F80;   // 1.0 in K slot 101
    }

    // this wave's 16 Whh1 B-frags -> registers (held for all 30 steps; AGPR-resident)
    short8 bf[4][4];   // [G][kt]
    floatx4 cst[RGn];  // cell state per rg, rows 4q+r, unit jcol
    const floatx4 zro = (floatx4){0.f, 0.f, 0.f, 0.f};
    if (wave < 7) {
        const short8* fr = (const short8*)ws;
#pragma unroll
        for (int G = 0; G < 4; ++G)
#pragma unroll
            for (int kt = 0; kt < 4; ++kt)
                bf[G][kt] = fr[((((G << 3) | wave) << 2) + kt) * 64 + lane];
#pragma unroll
        for (int rg = 0; rg < RGn; ++rg) cst[rg] = zro;
    }
    __syncthreads();   // h buffers ready (zero + seed)

    // ---- Phase 1: LSTM1, 30 steps, 1 barrier/step; t-loop unrolled x2 (fixed buffers) ----
    auto cell1 = [&](const unsigned short* __restrict__ hc,
                     unsigned short* __restrict__ hn, int t) {
        if (wave == 7) {
            // K-slot maintenance: hn[.,100] = x_{t+1}, hn[.,101] = 1.0 (32 rows, 2 slots, 64 lanes)
            int tn = (t < Tn - 1) ? t + 1 : t;
            int row = lane & 31;
            float xv = xl[tn * ROWS + row];
            unsigned short val = (lane < 32) ? f2bf(xv) : (unsigned short)0x3F80;
            hn[row * KP + 100 + (lane >> 5)] = val;
        } else {
#pragma unroll
            for (int rg = 0; rg < RGn; ++rg) {
                short8 af[4];   // A[m=l][k=kt*32+q*8+j], rows rg*16+m
#pragma unroll
                for (int kt = 0; kt < 4; ++kt)
                    af[kt] = *(const short8*)(hc + (rg * 16 + l) * KP + kt * 32 + q * 8);
                // ---- gate phase A: i (G0), g (G2) -> pc = sig(i)*tanh(g) ----
                floatx4 a0, a1;
                a0 = __builtin_amdgcn_mfma_f32_16x16x32_bf16(af[0], bf[0][0], zro, 0, 0, 0);
                a1 = __builtin_amdgcn_mfma_f32_16x16x32_bf16(af[0], bf[2][0], zro, 0, 0, 0);
#pragma unroll
                for (int kt = 1; kt < 4; ++kt) {
                    a0 = __builtin_amdgcn_mfma_f32_16x16x32_bf16(af[kt], bf[0][kt], a0, 0, 0, 0);
                    a1 = __builtin_amdgcn_mfma_f32_16x16x32_bf16(af[kt], bf[2][kt], a1, 0, 0, 0);
                }
                float pc[4];
#pragma unroll
                for (int r = 0; r < 4; ++r)
                    pc[r] = sig_(a0[r]) * tanh_(a1[r]);
                // ---- gate phase B: f (G1), o (G3) -> c, h ----
                a0 = __builtin_amdgcn_mfma_f32_16x16x32_bf16(af[0], bf[1][0], zro, 0, 0, 0);
                a1 = __builtin_amdgcn_mfma_f32_16x16x32_bf16(af[0], bf[3][0], zro, 0, 0, 0);
#pragma unroll
                for (int kt = 1; kt < 4; ++kt) {
                    a0 = __builtin_amdgcn_mfma_f32_16x16x32_bf16(af[kt], bf[1][kt], a0, 0, 0, 0);
                    a1 = __builtin_amdgcn_mfma_f32_16x16x32_bf16(af[kt], bf[3][kt], a1, 0, 0, 0);
                }
#pragma unroll
                for (int r = 0; r < 4; ++r) {
                    float cc = sig_(a0[r]) * cst[rg][r] + pc[r];
                    cst[rg][r] = cc;
                    if (jcol < Hn)   // pad columns (incl. wave6 l>=4) never written; stay zero
                        hn[(rg * 16 + 4 * q + r) * KP + jcol] = f2bf(sig_(a1[r]) * tanh_(cc));
                }
            }
        }
    };
    for (int tt = 0; tt < Tn; tt += 2) {
        cell1(hb0, hb1, tt);
        __syncthreads();
        cell1(hb1, hb0, tt + 1);
        __syncthreads();
    }

    // ---- Wih2 frags; gin2 = (bih2+bhh2 fold) + last·Wih2^T parked in LDS (wave-private n) ----
    if (wave < 7) {
        const short8* fr = (const short8*)((const char*)ws + FRAG_BYTES);
#pragma unroll
        for (int G = 0; G < 4; ++G)
#pragma unroll
            for (int kt = 0; kt < 4; ++kt)
                bf[G][kt] = fr[((((G << 3) | wave) << 2) + kt) * 64 + lane];
        const unsigned short* hl = hb0;   // last = h after t=29 (t=29 odd -> hn was hb0)
        // hl K-slots: 100 = stale x (Wih2 row 100 is zero -> harmless), 101 = 1.0 (bias fold)
#pragma unroll
        for (int rg = 0; rg < RGn; ++rg) {
            short8 af[4];
#pragma unroll
            for (int kt = 0; kt < 4; ++kt)
                af[kt] = *(const short8*)(hl + (rg * 16 + l) * KP + kt * 32 + q * 8);
            floatx4 acc[4];
#pragma unroll
            for (int G = 0; G < 4; ++G)
                acc[G] = __builtin_amdgcn_mfma_f32_16x16x32_bf16(af[0], bf[G][0], zro, 0, 0, 0);
#pragma unroll
            for (int kt = 1; kt < 4; ++kt)
#pragma unroll
                for (int G = 0; G < 4; ++G)
                    acc[G] = __builtin_amdgcn_mfma_f32_16x16x32_bf16(
                        af[kt], bf[G][kt], acc[G], 0, 0, 0);
#pragma unroll
            for (int G = 0; G < 4; ++G) {
                int n = G * 128 + jcol;
                uint2 pk;
                pk.x = (unsigned)f2bf(acc[G][0]) | ((unsigned)f2bf(acc[G][1]) << 16);
                pk.y = (unsigned)f2bf(acc[G][2]) | ((unsigned)f2bf(acc[G][3]) << 16);
                *(uint2*)(g2 + n * RP + rg * 16 + 4 * q) = pk;   // same wave reads it back
            }
        }
        // ---- Whh2 frags ----
        const short8* fr2 = (const short8*)((const char*)ws + 2 * FRAG_BYTES);
#pragma unroll
        for (int G = 0; G < 4; ++G)
#pragma unroll
            for (int kt = 0; kt < 4; ++kt)
                bf[G][kt] = fr2[((((G << 3) | wave) << 2) + kt) * 64 + lane];
    }

    // ---- Phase 2: LSTM2, 7 steps; FC2 runs on wave 7 ----
    // K-slots 100/101 of both h buffers retain phase-1 values (101=1.0 feeds the bias folds;
    // 100=stale x is multiplied by zero rows of Wih2/Whh2/W2). Pads 102..127 stay zero.
    const short8* w2fr = (const short8*)((const char*)ws + WS_W2_OFF);
    floatx4 yfc[RGn];
    if (wave == 7) {
#pragma unroll
        for (int rg = 0; rg < RGn; ++rg) yfc[rg] = zro;
    }

    for (int ps = 0; ps < Pn; ++ps) {
        int t = Tn + ps;
        const unsigned short* hc = (t & 1) ? hb1 : hb0;
        unsigned short* hn = (t & 1) ? hb0 : hb1;
        if (wave == 7) {
            if (ps >= 1) {   // hc holds h2 of step ps-1
                short8 w2f[4];
#pragma unroll
                for (int kt = 0; kt < 4; ++kt)
                    w2f[kt] = w2fr[((ps - 1) * 4 + kt) * 64 + lane];
#pragma unroll
                for (int rg = 0; rg < RGn; ++rg) {
                    short8 af2[4];
#pragma unroll
                    for (int kt = 0; kt < 4; ++kt)
                        af2[kt] = *(const short8*)(hc + (rg * 16 + l) * KP + kt * 32 + q * 8);
#pragma unroll
                    for (int kt = 0; kt < 4; ++kt)
                        yfc[rg] = __builtin_amdgcn_mfma_f32_16x16x32_bf16(
                            af2[kt], w2f[kt], yfc[rg], 0, 0, 0);
                }
            }
        } else {
#pragma unroll
            for (int rg = 0; rg < RGn; ++rg) {
                short8 af[4];
#pragma unroll
                for (int kt = 0; kt < 4; ++kt)
                    af[kt] = *(const short8*)(hc + (rg * 16 + l) * KP + kt * 32 + q * 8);
                // ---- gate phase A: i (G0), g (G2) ----
                floatx4 a0, a1;
                {
                    int n0 = 0 * 128 + jcol, n1 = 2 * 128 + jcol;
                    uint2 p0 = *(const uint2*)(g2 + n0 * RP + rg * 16 + 4 * q);
                    uint2 p1 = *(const uint2*)(g2 + n1 * RP + rg * 16 + 4 * q);
                    a0[0] = __uint_as_float(p0.x << 16);
                    a0[1] = __uint_as_float(p0.x & 0xFFFF0000u);
                    a0[2] = __uint_as_float(p0.y << 16);
                    a0[3] = __uint_as_float(p0.y & 0xFFFF0000u);
                    a1[0] = __uint_as_float(p1.x << 16);
                    a1[1] = __uint_as_float(p1.x & 0xFFFF0000u);
                    a1[2] = __uint_as_float(p1.y << 16);
                    a1[3] = __uint_as_float(p1.y & 0xFFFF0000u);
                }
#pragma unroll
                for (int kt = 0; kt < 4; ++kt) {
                    a0 = __builtin_amdgcn_mfma_f32_16x16x32_bf16(af[kt], bf[0][kt], a0, 0, 0, 0);
                    a1 = __builtin_amdgcn_mfma_f32_16x16x32_bf16(af[kt], bf[2][kt], a1, 0, 0, 0);
                }
                float pc[4];
#pragma unroll
                for (int r = 0; r < 4; ++r)
                    pc[r] = sig_(a0[r]) * tanh_(a1[r]);
                // ---- gate phase B: f (G1), o (G3) ----
                {
                    int n0 = 1 * 128 + jcol, n1 = 3 * 128 + jcol;
                    uint2 p0 = *(const uint2*)(g2 + n0 * RP + rg * 16 + 4 * q);
                    uint2 p1 = *(const uint2*)(g2 + n1 * RP + rg * 16 + 4 * q);
                    a0[0] = __uint_as_float(p0.x << 16);
                    a0[1] = __uint_as_float(p0.x & 0xFFFF0000u);
                    a0[2] = __uint_as_float(p0.y << 16);
                    a0[3] = __uint_as_float(p0.y & 0xFFFF0000u);
                    a1[0] = __uint_as_float(p1.x << 16);
                    a1[1] = __uint_as_float(p1.x & 0xFFFF0000u);
                    a1[2] = __uint_as_float(p1.y << 16);
                    a1[3] = __uint_as_float(p1.y & 0xFFFF0000u);
                }
#pragma unroll
                for (int kt = 0; kt < 4; ++kt) {
                    a0 = __builtin_amdgcn_mfma_f32_16x16x32_bf16(af[kt], bf[1][kt], a0, 0, 0, 0);
                    a1 = __builtin_amdgcn_mfma_f32_16x16x32_bf16(af[kt], bf[3][kt], a1, 0, 0, 0);
                }
#pragma unroll
                for (int r = 0; r < 4; ++r) {
                    float cc = sig_(a0[r]) * cst[rg][r] + pc[r];
                    cst[rg][r] = cc;
                    if (jcol < Hn)
                        hn[(rg * 16 + 4 * q + r) * KP + jcol] = f2bf(sig_(a1[r]) * tanh_(cc));
                }
            }
        }
        __syncthreads();
    }

    // ---- final FC2 for h2 of ps=6 (t=36 even -> hn=hb1); b2 folded into ps=6 frag k=101 ----
    if (wave == 7) {
        short8 w2f[4];
#pragma unroll
        for (int kt = 0; kt < 4; ++kt)
            w2f[kt] = w2fr[(6 * 4 + kt) * 64 + lane];
#pragma unroll
        for (int rg = 0; rg < RGn; ++rg) {
            short8 af2[4];
#pragma unroll
            for (int kt = 0; kt < 4; ++kt)
                af2[kt] = *(const short8*)(hb1 + (rg * 16 + l) * KP + kt * 32 + q * 8);
#pragma unroll
            for (int kt = 0; kt < 4; ++kt)
                yfc[rg] = __builtin_amdgcn_mfma_f32_16x16x32_bf16(
                    af2[kt], w2f[kt], yfc[rg], 0, 0, 0);
            if (l < Pn) {
#pragma unroll
                for (int r = 0; r < 4; ++r)
                    out[(rowbase + rg * 16 + 4 * q + r) * Pn + l] = sig_(yfc[rg][r]);
            }
        }
    }
}

extern "C" void kernel_launch(void* const* d_in, const int* in_sizes, int n_in,
                              void* d_out, int out_size, void* d_ws, size_t ws_size,
                              hipStream_t stream) {
    const float* x    = (const float*)d_in[0];
    const float* W1   = (const float*)d_in[1];
    const float* b1   = (const float*)d_in[2];
    const float* Wih1 = (const float*)d_in[3];
    const float* Whh1 = (const float*)d_in[4];
    const float* bih1 = (const float*)d_in[5];
    const float* bhh1 = (const float*)d_in[6];
    const float* Wih2 = (const float*)d_in[7];
    const float* Whh2 = (const float*)d_in[8];
    const float* bih2 = (const float*)d_in[9];
    const float* bhh2 = (const float*)d_in[10];
    const float* W2   = (const float*)d_in[11];
    const float* b2   = (const float*)d_in[12];
    float* out = (float*)d_out;
    float* ws  = (float*)d_ws;

    (void)hipFuncSetAttribute((const void*)lstm_fused,
                              hipFuncAttributeMaxDynamicSharedMemorySize, SMEM_BYTES);

    setup_kernel<<<PACK_BLOCKS, 256, 0, stream>>>(W1, b1, Wih1, bih1, bhh1,
                                                  bih2, bhh2, Whh1, Wih2, Whh2, W2, b2, ws);
    lstm_fused<<<Bn / ROWS, 512, SMEM_BYTES, stream>>>(x, ws, out);
}

// Round 7
// 184.110 us; speedup vs baseline: 1.2173x; 1.0791x over previous
//
#include <hip/hip_runtime.h>
#include <math.h>

// Problem constants
#define Tn 30
#define Bn 16384
#define Hn 100
#define Pn 7

// Tiling: gates padded 100->128 units => N=512 (32 n-tiles); K padded 100->128 (4 k-tiles of 32).
// K slots 100/101 carry the FC1 fold: A[k=100]=x_t(row), A[k=101]=1.0; Whh1 B rows 100/101 hold
// u1[j]/wc1[j]; Wih2 row 101 holds bih2+bhh2; W2(ps=6) row 101 holds b2.
// ROUND-7: all gate weights pre-scaled by log2e (gate g by 2*log2e, W2/b2 by log2e) so the MFMA
// emits exp2-ready pre-activations: activations use bare v_exp_f32 (exp2) with free negation,
// and sig*tanh products share one rcp: sig(i)tanh(g) = (e2g-1)/[(1+e-i)(e2g+1)].
// Trans/element 10 -> 8, no per-exp v_mul. (VALU-issue-bound: trans were ~half of VALU issue.)
// 32 rows/block (grid 512), 8 waves; wave w<7 owns units [16w,16w+16); wave 7 maintains K-slots
// in phase 1 and runs FC2 in phase 2. __launch_bounds__(512,4): 128 total regs/wave (64 arch +
// 64 acc for bf frags) => 2 blocks/CU = 4 waves/SIMD (register ceiling: 16 waves/CU).
#define ROWS 32           // rows per block
#define RGn 2             // row-groups of 16
#define KP 136            // h row pitch (ushorts); 272B -> 16B-aligned A-frag reads
#define RP 36             // gin2 row pitch (ushorts): 32 rows + 4 pad
#define NFRAG 128         // B-frags per matrix (32 nt x 4 kt)
#define FRAG_BYTES (NFRAG * 64 * 16)   // 131072 per matrix
#define WS_W2_OFF (3 * FRAG_BYTES)     // 28 W2 frags (7 ps x 4 kt)
#define HBUF_USH (ROWS * KP)           // 4352
#define G2_USH (512 * RP)              // 18432
#define XL_USH_OFF (2 * HBUF_USH + G2_USH)            // 27136 ushorts
#define SMEM_BYTES (XL_USH_OFF * 2 + Tn * ROWS * 4)   // 54272 + 3840 = 58112

#define PACK_BLOCKS 103   // (3*128*64 + 28*64)/256 exactly

#define LOG2E 1.4426950408889634f
#define LOG2E2 2.8853900817779268f   // 2*log2e

typedef __attribute__((ext_vector_type(8))) short short8;   // 8 bf16 (4 VGPRs)
typedef __attribute__((ext_vector_type(4))) float floatx4;  // MFMA C/D

__device__ __forceinline__ float rcp_(float v) { return __builtin_amdgcn_rcpf(v); }
__device__ __forceinline__ float e2_(float v) { return __builtin_amdgcn_exp2f(v); }
__device__ __forceinline__ unsigned short f2bf(float v) {
    unsigned int u = __float_as_uint(v);
    return (unsigned short)((u + 0x7FFFu + ((u >> 16) & 1u)) >> 16);   // RNE
}

// Pack the 3 recurrent matrices (400x100) into bf16 B-frag layout (gates padded to 128 units),
// with the bias/FC1 folds in padded K rows, ALL PRE-SCALED: gates i,f,o by log2e; gate g (G==2)
// by 2*log2e; W2/b2 by log2e. Folds:
//   mat 0 (Whh1): k=100 -> u1[j] = Wih1[j,:]·W1 ; k=101 -> wc1[j] = Wih1[j,:]·b1 + bih1[j] + bhh1[j]
//   mat 1 (Wih2): k=101 -> bih2[j] + bhh2[j]
//   W2 frags:     k=101 && ps==6 -> b2[p]   (A k=101 is 1.0 every step; add bias exactly once)
// B[k][n]: n = lane&15, k = (lane>>4)*8 + jj  (16x16x32 bf16 B mapping, HW-verified).
__global__ void setup_kernel(const float* __restrict__ W1,
                             const float* __restrict__ b1,
                             const float* __restrict__ Wih1,
                             const float* __restrict__ bih1,
                             const float* __restrict__ bhh1,
                             const float* __restrict__ bih2,
                             const float* __restrict__ bhh2,
                             const float* __restrict__ Whh1,
                             const float* __restrict__ Wih2,
                             const float* __restrict__ Whh2,
                             const float* __restrict__ W2,
                             const float* __restrict__ b2,
                             float* __restrict__ ws) {
    int gid = blockIdx.x * 256 + threadIdx.x;   // 3*128*64 + 28*64 = 26368
    int lane = gid & 63;
    int l = lane & 15, q = lane >> 4;
    unsigned short hh[8];
    uint4 u;
    if (gid < 3 * NFRAG * 64) {
        int mat = gid / (NFRAG * 64);
        int f = (gid % (NFRAG * 64)) >> 6;
        int nt = f >> 2, kt = f & 3;
        int G = nt >> 3, ag = nt & 7;
        int j = ag * 16 + l;                    // unit within gate
        int row = G * Hn + (j < Hn ? j : 0);    // row of the 400-row weight matrices
        const float sG = (G == 2) ? LOG2E2 : LOG2E;   // exp2 pre-scale (g gate carries the 2x)
        const float* W = (mat == 0) ? Whh1 : (mat == 1) ? Wih2 : Whh2;
        const float* wrow = W + row * Hn;
        float u1 = 0.f, wc1 = 0.f;
        if (mat == 0 && kt == 3 && q == 0 && j < Hn) {   // lanes producing k=100/101
            for (int k = 0; k < Hn; ++k) {
                float a = Wih1[row * Hn + k];
                u1 += a * W1[k];
                wc1 += a * b1[k];
            }
            wc1 += bih1[row] + bhh1[row];
        }
        int kbase = kt * 32 + q * 8;
#pragma unroll
        for (int jj = 0; jj < 8; ++jj) {
            int k = kbase + jj;
            unsigned short v = 0;
            if (j < Hn) {
                if (k < Hn) v = f2bf(wrow[k] * sG);
                else if (mat == 0 && k == 100) v = f2bf(u1 * sG);
                else if (mat == 0 && k == 101) v = f2bf(wc1 * sG);
                else if (mat == 1 && k == 101) v = f2bf((bih2[row] + bhh2[row]) * sG);
            }
            hh[jj] = v;
        }
        u.x = (unsigned)hh[0] | ((unsigned)hh[1] << 16);
        u.y = (unsigned)hh[2] | ((unsigned)hh[3] << 16);
        u.z = (unsigned)hh[4] | ((unsigned)hh[5] << 16);
        u.w = (unsigned)hh[6] | ((unsigned)hh[7] << 16);
        ((uint4*)((char*)ws + mat * FRAG_BYTES))[f * 64 + lane] = u;
    } else {
        int t = gid - 3 * NFRAG * 64;           // 0..1791
        int f = t >> 6;                         // 0..27 = ps*4 + kt
        int ps = f >> 2, kt = f & 3;
        int kbase = kt * 32 + q * 8;
#pragma unroll
        for (int jj = 0; jj < 8; ++jj) {
            int k = kbase + jj;
            unsigned short v = 0;
            if (l < Pn) {
                if (k < Hn) v = f2bf(W2[l * (Pn * Hn) + ps * Hn + k] * LOG2E);
                else if (k == 101 && ps == 6) v = f2bf(b2[l] * LOG2E);
            }
            hh[jj] = v;
        }
        u.x = (unsigned)hh[0] | ((unsigned)hh[1] << 16);
        u.y = (unsigned)hh[2] | ((unsigned)hh[3] << 16);
        u.z = (unsigned)hh[4] | ((unsigned)hh[5] << 16);
        u.w = (unsigned)hh[6] | ((unsigned)hh[7] << 16);
        ((uint4*)((char*)ws + WS_W2_OFF))[f * 64 + lane] = u;
    }
}

__global__ __launch_bounds__(512, 4) void lstm_fused(
    const float* __restrict__ x,     // (T,B)
    const float* __restrict__ ws,    // packed frags (+folds), exp2-prescaled
    float* __restrict__ out)         // (B,7)
{
    extern __shared__ unsigned short sm[];
    unsigned short* hb0 = sm;                   // h double buffer [row ROWS][k KP]
    unsigned short* hb1 = sm + HBUF_USH;
    unsigned short* g2 = sm + 2 * HBUF_USH;     // gin2 bf16 [n 512][row RP] (scaled units)
    float* xl = (float*)(sm + XL_USH_OFF);      // x slice [t 30][row 32]

    const int tid = threadIdx.x;
    const int wave = tid >> 6, lane = tid & 63;
    const int l = lane & 15, q = lane >> 4;
    const int jcol = wave * 16 + l;             // this wave's unit column (0..127)
    const int rowbase = blockIdx.x * ROWS;

    for (int i = tid; i < 2 * HBUF_USH; i += 512) sm[i] = 0;
    for (int i = tid; i < Tn * ROWS; i += 512)
        xl[i] = x[(i >> 5) * Bn + rowbase + (i & 31)];
    __syncthreads();   // zeroing + x staging done before seeding
    if (tid < ROWS) {
        hb0[tid * KP + 100] = f2bf(x[rowbase + tid]);   // x_0 in K slot 100
        hb0[tid * KP + 101] = (unsigned short)0x3F80;   // 1.0 in K slot 101
    }

    // this wave's 16 Whh1 B-frags -> registers (held for all 30 steps; AGPR-resident)
    short8 bf[4][4];   // [G][kt]
    floatx4 cst[RGn];  // cell state per rg, rows 4q+r, unit jcol
    const floatx4 zro = (floatx4){0.f, 0.f, 0.f, 0.f};
    if (wave < 7) {
        const short8* fr = (const short8*)ws;
#pragma unroll
        for (int G = 0; G < 4; ++G)
#pragma unroll
            for (int kt = 0; kt < 4; ++kt)
                bf[G][kt] = fr[((((G << 3) | wave) << 2) + kt) * 64 + lane];
#pragma unroll
        for (int rg = 0; rg < RGn; ++rg) cst[rg] = zro;
    }
    __syncthreads();   // h buffers ready (zero + seed)

    // ---- Phase 1: LSTM1, 30 steps, 1 barrier/step; t-loop unrolled x2 (fixed buffers) ----
    // Gate pre-activations arrive exp2-scaled: i',f',o' = gate*log2e; g' = gate*2*log2e.
    // sig(v) = 1/(1+2^-v'); tanh(g) = (2^g'-1)/(2^g'+1); products share one rcp.
    auto cell1 = [&](const unsigned short* __restrict__ hc,
                     unsigned short* __restrict__ hn, int t) {
        if (wave == 7) {
            // K-slot maintenance: hn[.,100] = x_{t+1}, hn[.,101] = 1.0
            int tn = (t < Tn - 1) ? t + 1 : t;
            int row = lane & 31;
            float xv = xl[tn * ROWS + row];
            unsigned short val = (lane < 32) ? f2bf(xv) : (unsigned short)0x3F80;
            hn[row * KP + 100 + (lane >> 5)] = val;
        } else {
#pragma unroll
            for (int rg = 0; rg < RGn; ++rg) {
                short8 af[4];   // A[m=l][k=kt*32+q*8+j], rows rg*16+m
#pragma unroll
                for (int kt = 0; kt < 4; ++kt)
                    af[kt] = *(const short8*)(hc + (rg * 16 + l) * KP + kt * 32 + q * 8);
                // ---- gate phase A: i (G0), g (G2) -> pc = sig(i)*tanh(g), merged rcp ----
                floatx4 a0, a1;
                a0 = __builtin_amdgcn_mfma_f32_16x16x32_bf16(af[0], bf[0][0], zro, 0, 0, 0);
                a1 = __builtin_amdgcn_mfma_f32_16x16x32_bf16(af[0], bf[2][0], zro, 0, 0, 0);
#pragma unroll
                for (int kt = 1; kt < 4; ++kt) {
                    a0 = __builtin_amdgcn_mfma_f32_16x16x32_bf16(af[kt], bf[0][kt], a0, 0, 0, 0);
                    a1 = __builtin_amdgcn_mfma_f32_16x16x32_bf16(af[kt], bf[2][kt], a1, 0, 0, 0);
                }
                float pc[4];
#pragma unroll
                for (int r = 0; r < 4; ++r) {
                    float ei = e2_(-a0[r]);
                    float eg = e2_(a1[r]);
                    pc[r] = (eg - 1.f) * rcp_((1.f + ei) * (1.f + eg));
                }
                // ---- gate phase B: f (G1), o (G3) -> c, h (merged rcp for sig(o)*tanh(c)) ----
                a0 = __builtin_amdgcn_mfma_f32_16x16x32_bf16(af[0], bf[1][0], zro, 0, 0, 0);
                a1 = __builtin_amdgcn_mfma_f32_16x16x32_bf16(af[0], bf[3][0], zro, 0, 0, 0);
#pragma unroll
                for (int kt = 1; kt < 4; ++kt) {
                    a0 = __builtin_amdgcn_mfma_f32_16x16x32_bf16(af[kt], bf[1][kt], a0, 0, 0, 0);
                    a1 = __builtin_amdgcn_mfma_f32_16x16x32_bf16(af[kt], bf[3][kt], a1, 0, 0, 0);
                }
#pragma unroll
                for (int r = 0; r < 4; ++r) {
                    float ef = e2_(-a0[r]);
                    float cc = cst[rg][r] * rcp_(1.f + ef) + pc[r];
                    cst[rg][r] = cc;
                    float eo = e2_(-a1[r]);
                    float ec = e2_(cc * LOG2E2);
                    float hv = (ec - 1.f) * rcp_((1.f + eo) * (1.f + ec));
                    if (jcol < Hn)   // pad columns never written; stay zero
                        hn[(rg * 16 + 4 * q + r) * KP + jcol] = f2bf(hv);
                }
            }
        }
    };
    for (int tt = 0; tt < Tn; tt += 2) {
        cell1(hb0, hb1, tt);
        __syncthreads();
        cell1(hb1, hb0, tt + 1);
        __syncthreads();
    }

    // ---- Wih2 frags; gin2 = (bih2+bhh2 fold) + last·Wih2^T parked in LDS (scaled units) ----
    if (wave < 7) {
        const short8* fr = (const short8*)((const char*)ws + FRAG_BYTES);
#pragma unroll
        for (int G = 0; G < 4; ++G)
#pragma unroll
            for (int kt = 0; kt < 4; ++kt)
                bf[G][kt] = fr[((((G << 3) | wave) << 2) + kt) * 64 + lane];
        const unsigned short* hl = hb0;   // last = h after t=29 (t=29 odd -> hn was hb0)
        // hl K-slots: 100 = stale x (Wih2 row 100 is zero -> harmless), 101 = 1.0 (bias fold)
#pragma unroll
        for (int rg = 0; rg < RGn; ++rg) {
            short8 af[4];
#pragma unroll
            for (int kt = 0; kt < 4; ++kt)
                af[kt] = *(const short8*)(hl + (rg * 16 + l) * KP + kt * 32 + q * 8);
            floatx4 acc[4];
#pragma unroll
            for (int G = 0; G < 4; ++G)
                acc[G] = __builtin_amdgcn_mfma_f32_16x16x32_bf16(af[0], bf[G][0], zro, 0, 0, 0);
#pragma unroll
            for (int kt = 1; kt < 4; ++kt)
#pragma unroll
                for (int G = 0; G < 4; ++G)
                    acc[G] = __builtin_amdgcn_mfma_f32_16x16x32_bf16(
                        af[kt], bf[G][kt], acc[G], 0, 0, 0);
#pragma unroll
            for (int G = 0; G < 4; ++G) {
                int n = G * 128 + jcol;
                uint2 pk;
                pk.x = (unsigned)f2bf(acc[G][0]) | ((unsigned)f2bf(acc[G][1]) << 16);
                pk.y = (unsigned)f2bf(acc[G][2]) | ((unsigned)f2bf(acc[G][3]) << 16);
                *(uint2*)(g2 + n * RP + rg * 16 + 4 * q) = pk;   // same wave reads it back
            }
        }
        // ---- Whh2 frags ----
        const short8* fr2 = (const short8*)((const char*)ws + 2 * FRAG_BYTES);
#pragma unroll
        for (int G = 0; G < 4; ++G)
#pragma unroll
            for (int kt = 0; kt < 4; ++kt)
                bf[G][kt] = fr2[((((G << 3) | wave) << 2) + kt) * 64 + lane];
    }

    // ---- Phase 2: LSTM2, 7 steps; FC2 runs on wave 7 ----
    const short8* w2fr = (const short8*)((const char*)ws + WS_W2_OFF);
    floatx4 yfc[RGn];
    if (wave == 7) {
#pragma unroll
        for (int rg = 0; rg < RGn; ++rg) yfc[rg] = zro;
    }

    for (int ps = 0; ps < Pn; ++ps) {
        int t = Tn + ps;
        const unsigned short* hc = (t & 1) ? hb1 : hb0;
        unsigned short* hn = (t & 1) ? hb0 : hb1;
        if (wave == 7) {
            if (ps >= 1) {   // hc holds h2 of step ps-1
                short8 w2f[4];
#pragma unroll
                for (int kt = 0; kt < 4; ++kt)
                    w2f[kt] = w2fr[((ps - 1) * 4 + kt) * 64 + lane];
#pragma unroll
                for (int rg = 0; rg < RGn; ++rg) {
                    short8 af2[4];
#pragma unroll
                    for (int kt = 0; kt < 4; ++kt)
                        af2[kt] = *(const short8*)(hc + (rg * 16 + l) * KP + kt * 32 + q * 8);
#pragma unroll
                    for (int kt = 0; kt < 4; ++kt)
                        yfc[rg] = __builtin_amdgcn_mfma_f32_16x16x32_bf16(
                            af2[kt], w2f[kt], yfc[rg], 0, 0, 0);
                }
            }
        } else {
#pragma unroll
            for (int rg = 0; rg < RGn; ++rg) {
                short8 af[4];
#pragma unroll
                for (int kt = 0; kt < 4; ++kt)
                    af[kt] = *(const short8*)(hc + (rg * 16 + l) * KP + kt * 32 + q * 8);
                // ---- gate phase A: i (G0), g (G2) ----
                floatx4 a0, a1;
                {
                    int n0 = 0 * 128 + jcol, n1 = 2 * 128 + jcol;
                    uint2 p0 = *(const uint2*)(g2 + n0 * RP + rg * 16 + 4 * q);
                    uint2 p1 = *(const uint2*)(g2 + n1 * RP + rg * 16 + 4 * q);
                    a0[0] = __uint_as_float(p0.x << 16);
                    a0[1] = __uint_as_float(p0.x & 0xFFFF0000u);
                    a0[2] = __uint_as_float(p0.y << 16);
                    a0[3] = __uint_as_float(p0.y & 0xFFFF0000u);
                    a1[0] = __uint_as_float(p1.x << 16);
                    a1[1] = __uint_as_float(p1.x & 0xFFFF0000u);
                    a1[2] = __uint_as_float(p1.y << 16);
                    a1[3] = __uint_as_float(p1.y & 0xFFFF0000u);
                }
#pragma unroll
                for (int kt = 0; kt < 4; ++kt) {
                    a0 = __builtin_amdgcn_mfma_f32_16x16x32_bf16(af[kt], bf[0][kt], a0, 0, 0, 0);
                    a1 = __builtin_amdgcn_mfma_f32_16x16x32_bf16(af[kt], bf[2][kt], a1, 0, 0, 0);
                }
                float pc[4];
#pragma unroll
                for (int r = 0; r < 4; ++r) {
                    float ei = e2_(-a0[r]);
                    float eg = e2_(a1[r]);
                    pc[r] = (eg - 1.f) * rcp_((1.f + ei) * (1.f + eg));
                }
                // ---- gate phase B: f (G1), o (G3) ----
                {
                    int n0 = 1 * 128 + jcol, n1 = 3 * 128 + jcol;
                    uint2 p0 = *(const uint2*)(g2 + n0 * RP + rg * 16 + 4 * q);
                    uint2 p1 = *(const uint2*)(g2 + n1 * RP + rg * 16 + 4 * q);
                    a0[0] = __uint_as_float(p0.x << 16);
                    a0[1] = __uint_as_float(p0.x & 0xFFFF0000u);
                    a0[2] = __uint_as_float(p0.y << 16);
                    a0[3] = __uint_as_float(p0.y & 0xFFFF0000u);
                    a1[0] = __uint_as_float(p1.x << 16);
                    a1[1] = __uint_as_float(p1.x & 0xFFFF0000u);
                    a1[2] = __uint_as_float(p1.y << 16);
                    a1[3] = __uint_as_float(p1.y & 0xFFFF0000u);
                }
#pragma unroll
                for (int kt = 0; kt < 4; ++kt) {
                    a0 = __builtin_amdgcn_mfma_f32_16x16x32_bf16(af[kt], bf[1][kt], a0, 0, 0, 0);
                    a1 = __builtin_amdgcn_mfma_f32_16x16x32_bf16(af[kt], bf[3][kt], a1, 0, 0, 0);
                }
#pragma unroll
                for (int r = 0; r < 4; ++r) {
                    float ef = e2_(-a0[r]);
                    float cc = cst[rg][r] * rcp_(1.f + ef) + pc[r];
                    cst[rg][r] = cc;
                    float eo = e2_(-a1[r]);
                    float ec = e2_(cc * LOG2E2);
                    float hv = (ec - 1.f) * rcp_((1.f + eo) * (1.f + ec));
                    if (jcol < Hn)
                        hn[(rg * 16 + 4 * q + r) * KP + jcol] = f2bf(hv);   // ps=6 too (final FC2)
                }
            }
        }
        __syncthreads();
    }

    // ---- final FC2 for h2 of ps=6 (t=36 even -> hn=hb1); b2 folded (scaled) into ps=6 k=101 ----
    if (wave == 7) {
        short8 w2f[4];
#pragma unroll
        for (int kt = 0; kt < 4; ++kt)
            w2f[kt] = w2fr[(6 * 4 + kt) * 64 + lane];
#pragma unroll
        for (int rg = 0; rg < RGn; ++rg) {
            short8 af2[4];
#pragma unroll
            for (int kt = 0; kt < 4; ++kt)
                af2[kt] = *(const short8*)(hb1 + (rg * 16 + l) * KP + kt * 32 + q * 8);
#pragma unroll
            for (int kt = 0; kt < 4; ++kt)
                yfc[rg] = __builtin_amdgcn_mfma_f32_16x16x32_bf16(
                    af2[kt], w2f[kt], yfc[rg], 0, 0, 0);
            if (l < Pn) {
#pragma unroll
                for (int r = 0; r < 4; ++r)   // y is log2e-scaled: sig = 1/(1+2^-y')
                    out[(rowbase + rg * 16 + 4 * q + r) * Pn + l] =
                        rcp_(1.f + e2_(-yfc[rg][r]));
            }
        }
    }
}

extern "C" void kernel_launch(void* const* d_in, const int* in_sizes, int n_in,
                              void* d_out, int out_size, void* d_ws, size_t ws_size,
                              hipStream_t stream) {
    const float* x    = (const float*)d_in[0];
    const float* W1   = (const float*)d_in[1];
    const float* b1   = (const float*)d_in[2];
    const float* Wih1 = (const float*)d_in[3];
    const float* Whh1 = (const float*)d_in[4];
    const float* bih1 = (const float*)d_in[5];
    const float* bhh1 = (const float*)d_in[6];
    const float* Wih2 = (const float*)d_in[7];
    const float* Whh2 = (const float*)d_in[8];
    const float* bih2 = (const float*)d_in[9];
    const float* bhh2 = (const float*)d_in[10];
    const float* W2   = (const float*)d_in[11];
    const float* b2   = (const float*)d_in[12];
    float* out = (float*)d_out;
    float* ws  = (float*)d_ws;

    (void)hipFuncSetAttribute((const void*)lstm_fused,
                              hipFuncAttributeMaxDynamicSharedMemorySize, SMEM_BYTES);

    setup_kernel<<<PACK_BLOCKS, 256, 0, stream>>>(W1, b1, Wih1, bih1, bhh1,
                                                  bih2, bhh2, Whh1, Wih2, Whh2, W2, b2, ws);
    lstm_fused<<<Bn / ROWS, 512, SMEM_BYTES, stream>>>(x, ws, out);
}

// Round 9
// 181.407 us; speedup vs baseline: 1.2354x; 1.0149x over previous
//
#include <hip/hip_runtime.h>
#include <math.h>

// Problem constants
#define Tn 30
#define Bn 16384
#define Hn 100
#define Pn 7

// Tiling: gates padded 100->128 units => N=512 (32 n-tiles); K padded 100->128 (4 k-tiles of 32).
// K slots 100/101 carry the FC1 fold: A[k=100]=x_t(row), A[k=101]=1.0; Whh1 B rows 100/101 hold
// u1[j]/wc1[j]; Wih2 row 101 holds bih2+bhh2; W2(ps=6) row 101 holds b2.
// Gate weights pre-scaled by log2e (gate g by 2*log2e, W2/b2 by log2e): activations use bare
// v_exp_f32 (exp2) with src-modifier negation; sig*tanh products share one rcp; denominators
// fma-folded (1+a)(1+b) = fma(t,b,t).
// ROUND-9: revert v_cvt_pk_bf16_f32 (round-8 NaN; unverified partial-write semantics) -> manual
// RNE f2bf (bit-exact, round-7-proven). Keep fma-fold + relaxed wave-6 store predicate (both
// analyzed safe). NEW: u1/wc1 dot products moved out of the pack kernel into a wave-parallel
// dots kernel (shuffle-reduce) -> removes the 100-iter serial chains from the setup pass.
// 32 rows/block (grid 512), 8 waves; wave w<7 owns units [16w,16w+16); wave 7 maintains K-slots
// in phase 1 and runs FC2 in phase 2. __launch_bounds__(512,4): 128 total regs/wave (64 arch +
// 64 acc for bf frags) => 2 blocks/CU = 4 waves/SIMD (register-file ceiling: 16 waves/CU).
#define ROWS 32           // rows per block
#define RGn 2             // row-groups of 16
#define KP 136            // h row pitch (ushorts); 272B -> 16B-aligned A-frag reads
#define RP 36             // gin2 row pitch (ushorts): 32 rows + 4 pad
#define NFRAG 128         // B-frags per matrix (32 nt x 4 kt)
#define FRAG_BYTES (NFRAG * 64 * 16)   // 131072 per matrix
#define WS_W2_OFF (3 * FRAG_BYTES)     // 28 W2 frags (7 ps x 4 kt)
#define WS_U_IDX ((WS_W2_OFF + 28 * 64 * 16) / 4)   // float index of u1[400] ++ wc1[400]
#define HBUF_USH (ROWS * KP)           // 4352
#define G2_USH (512 * RP)              // 18432
#define XL_USH_OFF (2 * HBUF_USH + G2_USH)            // 27136 ushorts
#define SMEM_BYTES (XL_USH_OFF * 2 + Tn * ROWS * 4)   // 54272 + 3840 = 58112

#define PACK_BLOCKS 103   // (3*128*64 + 28*64)/256 exactly

#define LOG2E 1.4426950408889634f
#define LOG2E2 2.8853900817779268f   // 2*log2e

typedef __attribute__((ext_vector_type(8))) short short8;   // 8 bf16 (4 VGPRs)
typedef __attribute__((ext_vector_type(4))) float floatx4;  // MFMA C/D

__device__ __forceinline__ float rcp_(float v) { return __builtin_amdgcn_rcpf(v); }
__device__ __forceinline__ float e2_(float v) { return __builtin_amdgcn_exp2f(v); }
__device__ __forceinline__ unsigned short f2bf(float v) {
    unsigned int u = __float_as_uint(v);
    return (unsigned short)((u + 0x7FFFu + ((u >> 16) & 1u)) >> 16);   // RNE
}

// Wave-parallel u1/wc1: row j handled by one 64-lane wave (400 waves total).
// ws[WS_U_IDX + j]       = u1[j]  = Wih1[j,:]·W1            (unscaled)
// ws[WS_U_IDX + 400 + j] = wc1[j] = Wih1[j,:]·b1 + bih1[j] + bhh1[j]
__global__ void dots_kernel(const float* __restrict__ W1,
                            const float* __restrict__ b1,
                            const float* __restrict__ Wih1,
                            const float* __restrict__ bih1,
                            const float* __restrict__ bhh1,
                            float* __restrict__ ws) {
    int wave = threadIdx.x >> 6, lane = threadIdx.x & 63;
    int j = blockIdx.x * 4 + wave;              // 100 blocks x 4 waves = 400 rows
    float u = 0.f, w = 0.f;
    for (int k = lane; k < Hn; k += 64) {
        float a = Wih1[j * Hn + k];
        u += a * W1[k];
        w += a * b1[k];
    }
#pragma unroll
    for (int m = 32; m; m >>= 1) {
        u += __shfl_xor(u, m);
        w += __shfl_xor(w, m);
    }
    if (lane == 0) {
        ws[WS_U_IDX + j] = u;
        ws[WS_U_IDX + 400 + j] = w + bih1[j] + bhh1[j];
    }
}

// Pack the 3 recurrent matrices (400x100) into bf16 B-frag layout (gates padded to 128 units),
// with the bias/FC1 folds in padded K rows, ALL PRE-SCALED: gates i,f,o by log2e; gate g (G==2)
// by 2*log2e; W2/b2 by log2e. Folds:
//   mat 0 (Whh1): k=100 -> u1[j] (from dots_kernel); k=101 -> wc1[j] (from dots_kernel)
//   mat 1 (Wih2): k=101 -> bih2[j] + bhh2[j]
//   W2 frags:     k=101 && ps==6 -> b2[p]   (A k=101 is 1.0 every step; add bias exactly once)
// B[k][n]: n = lane&15, k = (lane>>4)*8 + jj  (16x16x32 bf16 B mapping, HW-verified).
__global__ void setup_kernel(const float* __restrict__ bih2,
                             const float* __restrict__ bhh2,
                             const float* __restrict__ Whh1,
                             const float* __restrict__ Wih2,
                             const float* __restrict__ Whh2,
                             const float* __restrict__ W2,
                             const float* __restrict__ b2,
                             float* __restrict__ ws) {
    int gid = blockIdx.x * 256 + threadIdx.x;   // 3*128*64 + 28*64 = 26368
    int lane = gid & 63;
    int l = lane & 15, q = lane >> 4;
    unsigned short hh[8];
    uint4 u;
    if (gid < 3 * NFRAG * 64) {
        int mat = gid / (NFRAG * 64);
        int f = (gid % (NFRAG * 64)) >> 6;
        int nt = f >> 2, kt = f & 3;
        int G = nt >> 3, ag = nt & 7;
        int j = ag * 16 + l;                    // unit within gate
        int row = G * Hn + (j < Hn ? j : 0);    // row of the 400-row weight matrices
        const float sG = (G == 2) ? LOG2E2 : LOG2E;   // exp2 pre-scale (g gate carries the 2x)
        const float* W = (mat == 0) ? Whh1 : (mat == 1) ? Wih2 : Whh2;
        const float* wrow = W + row * Hn;
        int kbase = kt * 32 + q * 8;
#pragma unroll
        for (int jj = 0; jj < 8; ++jj) {
            int k = kbase + jj;
            unsigned short v = 0;
            if (j < Hn) {
                if (k < Hn) v = f2bf(wrow[k] * sG);
                else if (mat == 0 && k == 100) v = f2bf(ws[WS_U_IDX + row] * sG);
                else if (mat == 0 && k == 101) v = f2bf(ws[WS_U_IDX + 400 + row] * sG);
                else if (mat == 1 && k == 101) v = f2bf((bih2[row] + bhh2[row]) * sG);
            }
            hh[jj] = v;
        }
        u.x = (unsigned)hh[0] | ((unsigned)hh[1] << 16);
        u.y = (unsigned)hh[2] | ((unsigned)hh[3] << 16);
        u.z = (unsigned)hh[4] | ((unsigned)hh[5] << 16);
        u.w = (unsigned)hh[6] | ((unsigned)hh[7] << 16);
        ((uint4*)((char*)ws + mat * FRAG_BYTES))[f * 64 + lane] = u;
    } else {
        int t = gid - 3 * NFRAG * 64;           // 0..1791
        int f = t >> 6;                         // 0..27 = ps*4 + kt
        int ps = f >> 2, kt = f & 3;
        int kbase = kt * 32 + q * 8;
#pragma unroll
        for (int jj = 0; jj < 8; ++jj) {
            int k = kbase + jj;
            unsigned short v = 0;
            if (l < Pn) {
                if (k < Hn) v = f2bf(W2[l * (Pn * Hn) + ps * Hn + k] * LOG2E);
                else if (k == 101 && ps == 6) v = f2bf(b2[l] * LOG2E);
            }
            hh[jj] = v;
        }
        u.x = (unsigned)hh[0] | ((unsigned)hh[1] << 16);
        u.y = (unsigned)hh[2] | ((unsigned)hh[3] << 16);
        u.z = (unsigned)hh[4] | ((unsigned)hh[5] << 16);
        u.w = (unsigned)hh[6] | ((unsigned)hh[7] << 16);
        ((uint4*)((char*)ws + WS_W2_OFF))[f * 64 + lane] = u;
    }
}

__global__ __launch_bounds__(512, 4) void lstm_fused(
    const float* __restrict__ x,     // (T,B)
    const float* __restrict__ ws,    // packed frags (+folds), exp2-prescaled
    float* __restrict__ out)         // (B,7)
{
    extern __shared__ unsigned short sm[];
    unsigned short* hb0 = sm;                   // h double buffer [row ROWS][k KP]
    unsigned short* hb1 = sm + HBUF_USH;
    unsigned short* g2 = sm + 2 * HBUF_USH;     // gin2 bf16 [n 512][row RP] (scaled units)
    float* xl = (float*)(sm + XL_USH_OFF);      // x slice [t 30][row 32]

    const int tid = threadIdx.x;
    const int wave = tid >> 6, lane = tid & 63;
    const int l = lane & 15, q = lane >> 4;
    const int jcol = wave * 16 + l;             // this wave's unit column (0..127)
    const int rowbase = blockIdx.x * ROWS;
    // store predicate: waves 0-5 all-real; wave 6 must preserve cols 100/101 (x / 1.0 slots);
    // pad cols 102..111 take hv which is exactly 0 there (zero B cols -> zero preacts).
    const bool wr = (wave != 6) || (l < 4) || (l >= 6);

    for (int i = tid; i < 2 * HBUF_USH; i += 512) sm[i] = 0;
    for (int i = tid; i < Tn * ROWS; i += 512)
        xl[i] = x[(i >> 5) * Bn + rowbase + (i & 31)];
    __syncthreads();   // zeroing + x staging done before seeding
    if (tid < ROWS) {
        hb0[tid * KP + 100] = f2bf(x[rowbase + tid]);   // x_0 in K slot 100
        hb0[tid * KP + 101] = (unsigned short)0x3F80;   // 1.0 in K slot 101
    }

    // this wave's 16 Whh1 B-frags -> registers (held for all 30 steps; AGPR-resident)
    short8 bf[4][4];   // [G][kt]
    floatx4 cst[RGn];  // cell state per rg, rows 4q+r, unit jcol
    const floatx4 zro = (floatx4){0.f, 0.f, 0.f, 0.f};
    if (wave < 7) {
        const short8* fr = (const short8*)ws;
#pragma unroll
        for (int G = 0; G < 4; ++G)
#pragma unroll
            for (int kt = 0; kt < 4; ++kt)
                bf[G][kt] = fr[((((G << 3) | wave) << 2) + kt) * 64 + lane];
#pragma unroll
        for (int rg = 0; rg < RGn; ++rg) cst[rg] = zro;
    }
    __syncthreads();   // h buffers ready (zero + seed)

    // ---- Phase 1: LSTM1, 30 steps, 1 barrier/step; t-loop unrolled x2 (fixed buffers) ----
    // Gate pre-activations arrive exp2-scaled: i',f',o' = gate*log2e; g' = gate*2*log2e.
    // sig(v) = 1/(1+2^-v'); tanh(g) = (2^g'-1)/(2^g'+1); products share one rcp; denominators
    // use fma-fold (1+a)(1+b) = fma(t,b,t) with t=1+a.
    auto cell1 = [&](const unsigned short* __restrict__ hc,
                     unsigned short* __restrict__ hn, int t) {
        if (wave == 7) {
            // K-slot maintenance: hn[.,100] = x_{t+1}, hn[.,101] = 1.0
            int tn = (t < Tn - 1) ? t + 1 : t;
            int row = lane & 31;
            float xv = xl[tn * ROWS + row];
            unsigned short val = (lane < 32) ? f2bf(xv) : (unsigned short)0x3F80;
            hn[row * KP + 100 + (lane >> 5)] = val;
        } else {
#pragma unroll
            for (int rg = 0; rg < RGn; ++rg) {
                short8 af[4];   // A[m=l][k=kt*32+q*8+j], rows rg*16+m
#pragma unroll
                for (int kt = 0; kt < 4; ++kt)
                    af[kt] = *(const short8*)(hc + (rg * 16 + l) * KP + kt * 32 + q * 8);
                // ---- gate phase A: i (G0), g (G2) -> pc = sig(i)*tanh(g), merged rcp ----
                floatx4 a0, a1;
                a0 = __builtin_amdgcn_mfma_f32_16x16x32_bf16(af[0], bf[0][0], zro, 0, 0, 0);
                a1 = __builtin_amdgcn_mfma_f32_16x16x32_bf16(af[0], bf[2][0], zro, 0, 0, 0);
#pragma unroll
                for (int kt = 1; kt < 4; ++kt) {
                    a0 = __builtin_amdgcn_mfma_f32_16x16x32_bf16(af[kt], bf[0][kt], a0, 0, 0, 0);
                    a1 = __builtin_amdgcn_mfma_f32_16x16x32_bf16(af[kt], bf[2][kt], a1, 0, 0, 0);
                }
                float pc[4];
#pragma unroll
                for (int r = 0; r < 4; ++r) {
                    float ei = e2_(-a0[r]);
                    float eg = e2_(a1[r]);
                    float t1 = 1.f + ei;
                    pc[r] = (eg - 1.f) * rcp_(fmaf(t1, eg, t1));
                }
                // ---- gate phase B: f (G1), o (G3) -> c, h (merged rcp for sig(o)*tanh(c)) ----
                a0 = __builtin_amdgcn_mfma_f32_16x16x32_bf16(af[0], bf[1][0], zro, 0, 0, 0);
                a1 = __builtin_amdgcn_mfma_f32_16x16x32_bf16(af[0], bf[3][0], zro, 0, 0, 0);
#pragma unroll
                for (int kt = 1; kt < 4; ++kt) {
                    a0 = __builtin_amdgcn_mfma_f32_16x16x32_bf16(af[kt], bf[1][kt], a0, 0, 0, 0);
                    a1 = __builtin_amdgcn_mfma_f32_16x16x32_bf16(af[kt], bf[3][kt], a1, 0, 0, 0);
                }
#pragma unroll
                for (int r = 0; r < 4; ++r) {
                    float ef = e2_(-a0[r]);
                    float cc = fmaf(cst[rg][r], rcp_(1.f + ef), pc[r]);
                    cst[rg][r] = cc;
                    float eo = e2_(-a1[r]);
                    float ec = e2_(cc * LOG2E2);
                    float t2 = 1.f + eo;
                    float hv = (ec - 1.f) * rcp_(fmaf(t2, ec, t2));
                    if (wr)
                        hn[(rg * 16 + 4 * q + r) * KP + jcol] = f2bf(hv);
                }
            }
        }
    };
    for (int tt = 0; tt < Tn; tt += 2) {
        cell1(hb0, hb1, tt);
        __syncthreads();
        cell1(hb1, hb0, tt + 1);
        __syncthreads();
    }

    // ---- Wih2 frags; gin2 = (bih2+bhh2 fold) + last·Wih2^T parked in LDS (scaled units) ----
    if (wave < 7) {
        const short8* fr = (const short8*)((const char*)ws + FRAG_BYTES);
#pragma unroll
        for (int G = 0; G < 4; ++G)
#pragma unroll
            for (int kt = 0; kt < 4; ++kt)
                bf[G][kt] = fr[((((G << 3) | wave) << 2) + kt) * 64 + lane];
        const unsigned short* hl = hb0;   // last = h after t=29 (t=29 odd -> hn was hb0)
        // hl K-slots: 100 = stale x (Wih2 row 100 is zero -> harmless), 101 = 1.0 (bias fold)
#pragma unroll
        for (int rg = 0; rg < RGn; ++rg) {
            short8 af[4];
#pragma unroll
            for (int kt = 0; kt < 4; ++kt)
                af[kt] = *(const short8*)(hl + (rg * 16 + l) * KP + kt * 32 + q * 8);
            floatx4 acc[4];
#pragma unroll
            for (int G = 0; G < 4; ++G)
                acc[G] = __builtin_amdgcn_mfma_f32_16x16x32_bf16(af[0], bf[G][0], zro, 0, 0, 0);
#pragma unroll
            for (int kt = 1; kt < 4; ++kt)
#pragma unroll
                for (int G = 0; G < 4; ++G)
                    acc[G] = __builtin_amdgcn_mfma_f32_16x16x32_bf16(
                        af[kt], bf[G][kt], acc[G], 0, 0, 0);
#pragma unroll
            for (int G = 0; G < 4; ++G) {
                int n = G * 128 + jcol;
                uint2 pk;
                pk.x = (unsigned)f2bf(acc[G][0]) | ((unsigned)f2bf(acc[G][1]) << 16);
                pk.y = (unsigned)f2bf(acc[G][2]) | ((unsigned)f2bf(acc[G][3]) << 16);
                *(uint2*)(g2 + n * RP + rg * 16 + 4 * q) = pk;   // same wave reads it back
            }
        }
        // ---- Whh2 frags ----
        const short8* fr2 = (const short8*)((const char*)ws + 2 * FRAG_BYTES);
#pragma unroll
        for (int G = 0; G < 4; ++G)
#pragma unroll
            for (int kt = 0; kt < 4; ++kt)
                bf[G][kt] = fr2[((((G << 3) | wave) << 2) + kt) * 64 + lane];
    }

    // ---- Phase 2: LSTM2, 7 steps; FC2 runs on wave 7 ----
    // K-slots 100/101 retain phase-1 values (101=1.0 feeds bias folds; 100=stale x hits zero
    // weight rows). Pad cols: zero preacts -> hv=0 (garbage-free as in phase 1).
    const short8* w2fr = (const short8*)((const char*)ws + WS_W2_OFF);
    floatx4 yfc[RGn];
    if (wave == 7) {
#pragma unroll
        for (int rg = 0; rg < RGn; ++rg) yfc[rg] = zro;
    }

    for (int ps = 0; ps < Pn; ++ps) {
        int t = Tn + ps;
        const unsigned short* hc = (t & 1) ? hb1 : hb0;
        unsigned short* hn = (t & 1) ? hb0 : hb1;
        if (wave == 7) {
            if (ps >= 1) {   // hc holds h2 of step ps-1
                short8 w2f[4];
#pragma unroll
                for (int kt = 0; kt < 4; ++kt)
                    w2f[kt] = w2fr[((ps - 1) * 4 + kt) * 64 + lane];
#pragma unroll
                for (int rg = 0; rg < RGn; ++rg) {
                    short8 af2[4];
#pragma unroll
                    for (int kt = 0; kt < 4; ++kt)
                        af2[kt] = *(const short8*)(hc + (rg * 16 + l) * KP + kt * 32 + q * 8);
#pragma unroll
                    for (int kt = 0; kt < 4; ++kt)
                        yfc[rg] = __builtin_amdgcn_mfma_f32_16x16x32_bf16(
                            af2[kt], w2f[kt], yfc[rg], 0, 0, 0);
                }
            }
        } else {
#pragma unroll
            for (int rg = 0; rg < RGn; ++rg) {
                short8 af[4];
#pragma unroll
                for (int kt = 0; kt < 4; ++kt)
                    af[kt] = *(const short8*)(hc + (rg * 16 + l) * KP + kt * 32 + q * 8);
                // ---- gate phase A: i (G0), g (G2) ----
                floatx4 a0, a1;
                {
                    int n0 = 0 * 128 + jcol, n1 = 2 * 128 + jcol;
                    uint2 p0 = *(const uint2*)(g2 + n0 * RP + rg * 16 + 4 * q);
                    uint2 p1 = *(const uint2*)(g2 + n1 * RP + rg * 16 + 4 * q);
                    a0[0] = __uint_as_float(p0.x << 16);
                    a0[1] = __uint_as_float(p0.x & 0xFFFF0000u);
                    a0[2] = __uint_as_float(p0.y << 16);
                    a0[3] = __uint_as_float(p0.y & 0xFFFF0000u);
                    a1[0] = __uint_as_float(p1.x << 16);
                    a1[1] = __uint_as_float(p1.x & 0xFFFF0000u);
                    a1[2] = __uint_as_float(p1.y << 16);
                    a1[3] = __uint_as_float(p1.y & 0xFFFF0000u);
                }
#pragma unroll
                for (int kt = 0; kt < 4; ++kt) {
                    a0 = __builtin_amdgcn_mfma_f32_16x16x32_bf16(af[kt], bf[0][kt], a0, 0, 0, 0);
                    a1 = __builtin_amdgcn_mfma_f32_16x16x32_bf16(af[kt], bf[2][kt], a1, 0, 0, 0);
                }
                float pc[4];
#pragma unroll
                for (int r = 0; r < 4; ++r) {
                    float ei = e2_(-a0[r]);
                    float eg = e2_(a1[r]);
                    float t1 = 1.f + ei;
                    pc[r] = (eg - 1.f) * rcp_(fmaf(t1, eg, t1));
                }
                // ---- gate phase B: f (G1), o (G3) ----
                {
                    int n0 = 1 * 128 + jcol, n1 = 3 * 128 + jcol;
                    uint2 p0 = *(const uint2*)(g2 + n0 * RP + rg * 16 + 4 * q);
                    uint2 p1 = *(const uint2*)(g2 + n1 * RP + rg * 16 + 4 * q);
                    a0[0] = __uint_as_float(p0.x << 16);
                    a0[1] = __uint_as_float(p0.x & 0xFFFF0000u);
                    a0[2] = __uint_as_float(p0.y << 16);
                    a0[3] = __uint_as_float(p0.y & 0xFFFF0000u);
                    a1[0] = __uint_as_float(p1.x << 16);
                    a1[1] = __uint_as_float(p1.x & 0xFFFF0000u);
                    a1[2] = __uint_as_float(p1.y << 16);
                    a1[3] = __uint_as_float(p1.y & 0xFFFF0000u);
                }
#pragma unroll
                for (int kt = 0; kt < 4; ++kt) {
                    a0 = __builtin_amdgcn_mfma_f32_16x16x32_bf16(af[kt], bf[1][kt], a0, 0, 0, 0);
                    a1 = __builtin_amdgcn_mfma_f32_16x16x32_bf16(af[kt], bf[3][kt], a1, 0, 0, 0);
                }
#pragma unroll
                for (int r = 0; r < 4; ++r) {
                    float ef = e2_(-a0[r]);
                    float cc = fmaf(cst[rg][r], rcp_(1.f + ef), pc[r]);
                    cst[rg][r] = cc;
                    float eo = e2_(-a1[r]);
                    float ec = e2_(cc * LOG2E2);
                    float t2 = 1.f + eo;
                    float hv = (ec - 1.f) * rcp_(fmaf(t2, ec, t2));
                    if (wr)
                        hn[(rg * 16 + 4 * q + r) * KP + jcol] = f2bf(hv);   // ps=6 too
                }
            }
        }
        __syncthreads();
    }

    // ---- final FC2 for h2 of ps=6 (t=36 even -> hn=hb1); b2 folded (scaled) into ps=6 k=101 ----
    if (wave == 7) {
        short8 w2f[4];
#pragma unroll
        for (int kt = 0; kt < 4; ++kt)
            w2f[kt] = w2fr[(6 * 4 + kt) * 64 + lane];
#pragma unroll
        for (int rg = 0; rg < RGn; ++rg) {
            short8 af2[4];
#pragma unroll
            for (int kt = 0; kt < 4; ++kt)
                af2[kt] = *(const short8*)(hb1 + (rg * 16 + l) * KP + kt * 32 + q * 8);
#pragma unroll
            for (int kt = 0; kt < 4; ++kt)
                yfc[rg] = __builtin_amdgcn_mfma_f32_16x16x32_bf16(
                    af2[kt], w2f[kt], yfc[rg], 0, 0, 0);
            if (l < Pn) {
#pragma unroll
                for (int r = 0; r < 4; ++r)   // y is log2e-scaled: sig = 1/(1+2^-y')
                    out[(rowbase + rg * 16 + 4 * q + r) * Pn + l] =
                        rcp_(1.f + e2_(-yfc[rg][r]));
            }
        }
    }
}

extern "C" void kernel_launch(void* const* d_in, const int* in_sizes, int n_in,
                              void* d_out, int out_size, void* d_ws, size_t ws_size,
                              hipStream_t stream) {
    const float* x    = (const float*)d_in[0];
    const float* W1   = (const float*)d_in[1];
    const float* b1   = (const float*)d_in[2];
    const float* Wih1 = (const float*)d_in[3];
    const float* Whh1 = (const float*)d_in[4];
    const float* bih1 = (const float*)d_in[5];
    const float* bhh1 = (const float*)d_in[6];
    const float* Wih2 = (const float*)d_in[7];
    const float* Whh2 = (const float*)d_in[8];
    const float* bih2 = (const float*)d_in[9];
    const float* bhh2 = (const float*)d_in[10];
    const float* W2   = (const float*)d_in[11];
    const float* b2   = (const float*)d_in[12];
    float* out = (float*)d_out;
    float* ws  = (float*)d_ws;

    (void)hipFuncSetAttribute((const void*)lstm_fused,
                              hipFuncAttributeMaxDynamicSharedMemorySize, SMEM_BYTES);

    dots_kernel<<<100, 256, 0, stream>>>(W1, b1, Wih1, bih1, bhh1, ws);
    setup_kernel<<<PACK_BLOCKS, 256, 0, stream>>>(bih2, bhh2, Whh1, Wih2, Whh2, W2, b2, ws);
    lstm_fused<<<Bn / ROWS, 512, SMEM_BYTES, stream>>>(x, ws, out);
}

// Round 10
// 175.328 us; speedup vs baseline: 1.2782x; 1.0347x over previous
//
#include <hip/hip_runtime.h>
#include <math.h>

// Problem constants
#define Tn 30
#define Bn 16384
#define Hn 100
#define Pn 7

// Tiling: gates padded 100->128 units => N=512 (32 n-tiles); K padded 100->128 (4 k-tiles of 32).
// K slots 100/101 carry the FC1 fold: A[k=100]=x_t(row), A[k=101]=1.0; Whh1 B rows 100/101 hold
// u1[j]/wc1[j]; Wih2 row 101 holds bih2+bhh2; W2(ps=6) row 101 holds b2.
// Gate weights pre-scaled by log2e (gate g by 2*log2e, W2/b2 by log2e): activations use bare
// v_exp_f32 (exp2) with src-modifier negation; sig*tanh products share one rcp; denominators
// fma-folded (1+a)(1+b) = fma(t,b,t).
// ROUND-10: gate phases RE-MERGED (4 simultaneous accumulators): one contiguous 16-MFMA burst
// (4 independent chains) + one trans epilogue per rg. Affordable now that rounds 6-9 freed the
// arch regs (peak live ~54 < 64 cap); improves in-order-issue overlap (waves' MFMA bursts fill
// other waves' trans sections). Same per-element ops/order -> bit-identical. dots folded back
// into setup_kernel (extra launch cost ~2.5us > hidden serial-dot cost).
// 32 rows/block (grid 512), 8 waves; wave w<7 owns units [16w,16w+16); wave 7 maintains K-slots
// in phase 1 and runs FC2 in phase 2. __launch_bounds__(512,4): 128 total regs/wave (64 arch +
// 64 acc for bf frags) => 2 blocks/CU = 4 waves/SIMD (register-file ceiling: 16 waves/CU).
#define ROWS 32           // rows per block
#define RGn 2             // row-groups of 16
#define KP 136            // h row pitch (ushorts); 272B -> 16B-aligned A-frag reads
#define RP 36             // gin2 row pitch (ushorts): 32 rows + 4 pad
#define NFRAG 128         // B-frags per matrix (32 nt x 4 kt)
#define FRAG_BYTES (NFRAG * 64 * 16)   // 131072 per matrix
#define WS_W2_OFF (3 * FRAG_BYTES)     // 28 W2 frags (7 ps x 4 kt)
#define HBUF_USH (ROWS * KP)           // 4352
#define G2_USH (512 * RP)              // 18432
#define XL_USH_OFF (2 * HBUF_USH + G2_USH)            // 27136 ushorts
#define SMEM_BYTES (XL_USH_OFF * 2 + Tn * ROWS * 4)   // 54272 + 3840 = 58112

#define PACK_BLOCKS 103   // (3*128*64 + 28*64)/256 exactly

#define LOG2E 1.4426950408889634f
#define LOG2E2 2.8853900817779268f   // 2*log2e

typedef __attribute__((ext_vector_type(8))) short short8;   // 8 bf16 (4 VGPRs)
typedef __attribute__((ext_vector_type(4))) float floatx4;  // MFMA C/D

__device__ __forceinline__ float rcp_(float v) { return __builtin_amdgcn_rcpf(v); }
__device__ __forceinline__ float e2_(float v) { return __builtin_amdgcn_exp2f(v); }
__device__ __forceinline__ unsigned short f2bf(float v) {
    unsigned int u = __float_as_uint(v);
    return (unsigned short)((u + 0x7FFFu + ((u >> 16) & 1u)) >> 16);   // RNE
}

// Pack the 3 recurrent matrices (400x100) into bf16 B-frag layout (gates padded to 128 units),
// with the bias/FC1 folds in padded K rows, ALL PRE-SCALED: gates i,f,o by log2e; gate g (G==2)
// by 2*log2e; W2/b2 by log2e. Folds:
//   mat 0 (Whh1): k=100 -> u1[j] = Wih1[j,:]·W1 ; k=101 -> wc1[j] = Wih1[j,:]·b1 + bih1[j] + bhh1[j]
//   mat 1 (Wih2): k=101 -> bih2[j] + bhh2[j]
//   W2 frags:     k=101 && ps==6 -> b2[p]   (A k=101 is 1.0 every step; add bias exactly once)
// B[k][n]: n = lane&15, k = (lane>>4)*8 + jj  (16x16x32 bf16 B mapping, HW-verified).
__global__ void setup_kernel(const float* __restrict__ W1,
                             const float* __restrict__ b1,
                             const float* __restrict__ Wih1,
                             const float* __restrict__ bih1,
                             const float* __restrict__ bhh1,
                             const float* __restrict__ bih2,
                             const float* __restrict__ bhh2,
                             const float* __restrict__ Whh1,
                             const float* __restrict__ Wih2,
                             const float* __restrict__ Whh2,
                             const float* __restrict__ W2,
                             const float* __restrict__ b2,
                             float* __restrict__ ws) {
    int gid = blockIdx.x * 256 + threadIdx.x;   // 3*128*64 + 28*64 = 26368
    int lane = gid & 63;
    int l = lane & 15, q = lane >> 4;
    unsigned short hh[8];
    uint4 u;
    if (gid < 3 * NFRAG * 64) {
        int mat = gid / (NFRAG * 64);
        int f = (gid % (NFRAG * 64)) >> 6;
        int nt = f >> 2, kt = f & 3;
        int G = nt >> 3, ag = nt & 7;
        int j = ag * 16 + l;                    // unit within gate
        int row = G * Hn + (j < Hn ? j : 0);    // row of the 400-row weight matrices
        const float sG = (G == 2) ? LOG2E2 : LOG2E;   // exp2 pre-scale (g gate carries the 2x)
        const float* W = (mat == 0) ? Whh1 : (mat == 1) ? Wih2 : Whh2;
        const float* wrow = W + row * Hn;
        float u1 = 0.f, wc1 = 0.f;
        if (mat == 0 && kt == 3 && q == 0 && j < Hn) {   // lanes producing k=100/101
            for (int k = 0; k < Hn; ++k) {
                float a = Wih1[row * Hn + k];
                u1 += a * W1[k];
                wc1 += a * b1[k];
            }
            wc1 += bih1[row] + bhh1[row];
        }
        int kbase = kt * 32 + q * 8;
#pragma unroll
        for (int jj = 0; jj < 8; ++jj) {
            int k = kbase + jj;
            unsigned short v = 0;
            if (j < Hn) {
                if (k < Hn) v = f2bf(wrow[k] * sG);
                else if (mat == 0 && k == 100) v = f2bf(u1 * sG);
                else if (mat == 0 && k == 101) v = f2bf(wc1 * sG);
                else if (mat == 1 && k == 101) v = f2bf((bih2[row] + bhh2[row]) * sG);
            }
            hh[jj] = v;
        }
        u.x = (unsigned)hh[0] | ((unsigned)hh[1] << 16);
        u.y = (unsigned)hh[2] | ((unsigned)hh[3] << 16);
        u.z = (unsigned)hh[4] | ((unsigned)hh[5] << 16);
        u.w = (unsigned)hh[6] | ((unsigned)hh[7] << 16);
        ((uint4*)((char*)ws + mat * FRAG_BYTES))[f * 64 + lane] = u;
    } else {
        int t = gid - 3 * NFRAG * 64;           // 0..1791
        int f = t >> 6;                         // 0..27 = ps*4 + kt
        int ps = f >> 2, kt = f & 3;
        int kbase = kt * 32 + q * 8;
#pragma unroll
        for (int jj = 0; jj < 8; ++jj) {
            int k = kbase + jj;
            unsigned short v = 0;
            if (l < Pn) {
                if (k < Hn) v = f2bf(W2[l * (Pn * Hn) + ps * Hn + k] * LOG2E);
                else if (k == 101 && ps == 6) v = f2bf(b2[l] * LOG2E);
            }
            hh[jj] = v;
        }
        u.x = (unsigned)hh[0] | ((unsigned)hh[1] << 16);
        u.y = (unsigned)hh[2] | ((unsigned)hh[3] << 16);
        u.z = (unsigned)hh[4] | ((unsigned)hh[5] << 16);
        u.w = (unsigned)hh[6] | ((unsigned)hh[7] << 16);
        ((uint4*)((char*)ws + WS_W2_OFF))[f * 64 + lane] = u;
    }
}

__global__ __launch_bounds__(512, 4) void lstm_fused(
    const float* __restrict__ x,     // (T,B)
    const float* __restrict__ ws,    // packed frags (+folds), exp2-prescaled
    float* __restrict__ out)         // (B,7)
{
    extern __shared__ unsigned short sm[];
    unsigned short* hb0 = sm;                   // h double buffer [row ROWS][k KP]
    unsigned short* hb1 = sm + HBUF_USH;
    unsigned short* g2 = sm + 2 * HBUF_USH;     // gin2 bf16 [n 512][row RP] (scaled units)
    float* xl = (float*)(sm + XL_USH_OFF);      // x slice [t 30][row 32]

    const int tid = threadIdx.x;
    const int wave = tid >> 6, lane = tid & 63;
    const int l = lane & 15, q = lane >> 4;
    const int jcol = wave * 16 + l;             // this wave's unit column (0..127)
    const int rowbase = blockIdx.x * ROWS;
    // store predicate: waves 0-5 all-real; wave 6 must preserve cols 100/101 (x / 1.0 slots);
    // pad cols 102..111 take hv which is exactly 0 there (zero B cols -> zero preacts).
    const bool wr = (wave != 6) || (l < 4) || (l >= 6);

    for (int i = tid; i < 2 * HBUF_USH; i += 512) sm[i] = 0;
    for (int i = tid; i < Tn * ROWS; i += 512)
        xl[i] = x[(i >> 5) * Bn + rowbase + (i & 31)];
    __syncthreads();   // zeroing + x staging done before seeding
    if (tid < ROWS) {
        hb0[tid * KP + 100] = f2bf(x[rowbase + tid]);   // x_0 in K slot 100
        hb0[tid * KP + 101] = (unsigned short)0x3F80;   // 1.0 in K slot 101
    }

    // this wave's 16 Whh1 B-frags -> registers (held for all 30 steps; AGPR-resident)
    short8 bf[4][4];   // [G][kt]
    floatx4 cst[RGn];  // cell state per rg, rows 4q+r, unit jcol
    const floatx4 zro = (floatx4){0.f, 0.f, 0.f, 0.f};
    if (wave < 7) {
        const short8* fr = (const short8*)ws;
#pragma unroll
        for (int G = 0; G < 4; ++G)
#pragma unroll
            for (int kt = 0; kt < 4; ++kt)
                bf[G][kt] = fr[((((G << 3) | wave) << 2) + kt) * 64 + lane];
#pragma unroll
        for (int rg = 0; rg < RGn; ++rg) cst[rg] = zro;
    }
    __syncthreads();   // h buffers ready (zero + seed)

    // ---- Phase 1: LSTM1, 30 steps, 1 barrier/step; t-loop unrolled x2 (fixed buffers) ----
    // Gate pre-activations arrive exp2-scaled: i',f',o' = gate*log2e; g' = gate*2*log2e.
    // sig(v) = 1/(1+2^-v'); tanh(g) = (2^g'-1)/(2^g'+1); products share one rcp; denominators
    // use fma-fold (1+a)(1+b) = fma(t,b,t) with t=1+a. All 4 gates accumulate simultaneously:
    // one 16-MFMA burst (4 independent chains) then one trans epilogue.
    auto cell1 = [&](const unsigned short* __restrict__ hc,
                     unsigned short* __restrict__ hn, int t) {
        if (wave == 7) {
            // K-slot maintenance: hn[.,100] = x_{t+1}, hn[.,101] = 1.0
            int tn = (t < Tn - 1) ? t + 1 : t;
            int row = lane & 31;
            float xv = xl[tn * ROWS + row];
            unsigned short val = (lane < 32) ? f2bf(xv) : (unsigned short)0x3F80;
            hn[row * KP + 100 + (lane >> 5)] = val;
        } else {
#pragma unroll
            for (int rg = 0; rg < RGn; ++rg) {
                short8 af[4];   // A[m=l][k=kt*32+q*8+j], rows rg*16+m
#pragma unroll
                for (int kt = 0; kt < 4; ++kt)
                    af[kt] = *(const short8*)(hc + (rg * 16 + l) * KP + kt * 32 + q * 8);
                floatx4 A0, A1, A2, A3;   // gates i, f, g, o
                A0 = __builtin_amdgcn_mfma_f32_16x16x32_bf16(af[0], bf[0][0], zro, 0, 0, 0);
                A1 = __builtin_amdgcn_mfma_f32_16x16x32_bf16(af[0], bf[1][0], zro, 0, 0, 0);
                A2 = __builtin_amdgcn_mfma_f32_16x16x32_bf16(af[0], bf[2][0], zro, 0, 0, 0);
                A3 = __builtin_amdgcn_mfma_f32_16x16x32_bf16(af[0], bf[3][0], zro, 0, 0, 0);
#pragma unroll
                for (int kt = 1; kt < 4; ++kt) {
                    A0 = __builtin_amdgcn_mfma_f32_16x16x32_bf16(af[kt], bf[0][kt], A0, 0, 0, 0);
                    A1 = __builtin_amdgcn_mfma_f32_16x16x32_bf16(af[kt], bf[1][kt], A1, 0, 0, 0);
                    A2 = __builtin_amdgcn_mfma_f32_16x16x32_bf16(af[kt], bf[2][kt], A2, 0, 0, 0);
                    A3 = __builtin_amdgcn_mfma_f32_16x16x32_bf16(af[kt], bf[3][kt], A3, 0, 0, 0);
                }
#pragma unroll
                for (int r = 0; r < 4; ++r) {
                    float ei = e2_(-A0[r]);
                    float eg = e2_(A2[r]);
                    float t1 = 1.f + ei;
                    float pc = (eg - 1.f) * rcp_(fmaf(t1, eg, t1));
                    float ef = e2_(-A1[r]);
                    float cc = fmaf(cst[rg][r], rcp_(1.f + ef), pc);
                    cst[rg][r] = cc;
                    float eo = e2_(-A3[r]);
                    float ec = e2_(cc * LOG2E2);
                    float t2 = 1.f + eo;
                    float hv = (ec - 1.f) * rcp_(fmaf(t2, ec, t2));
                    if (wr)
                        hn[(rg * 16 + 4 * q + r) * KP + jcol] = f2bf(hv);
                }
            }
        }
    };
    for (int tt = 0; tt < Tn; tt += 2) {
        cell1(hb0, hb1, tt);
        __syncthreads();
        cell1(hb1, hb0, tt + 1);
        __syncthreads();
    }

    // ---- Wih2 frags; gin2 = (bih2+bhh2 fold) + last·Wih2^T parked in LDS (scaled units) ----
    if (wave < 7) {
        const short8* fr = (const short8*)((const char*)ws + FRAG_BYTES);
#pragma unroll
        for (int G = 0; G < 4; ++G)
#pragma unroll
            for (int kt = 0; kt < 4; ++kt)
                bf[G][kt] = fr[((((G << 3) | wave) << 2) + kt) * 64 + lane];
        const unsigned short* hl = hb0;   // last = h after t=29 (t=29 odd -> hn was hb0)
        // hl K-slots: 100 = stale x (Wih2 row 100 is zero -> harmless), 101 = 1.0 (bias fold)
#pragma unroll
        for (int rg = 0; rg < RGn; ++rg) {
            short8 af[4];
#pragma unroll
            for (int kt = 0; kt < 4; ++kt)
                af[kt] = *(const short8*)(hl + (rg * 16 + l) * KP + kt * 32 + q * 8);
            floatx4 acc[4];
#pragma unroll
            for (int G = 0; G < 4; ++G)
                acc[G] = __builtin_amdgcn_mfma_f32_16x16x32_bf16(af[0], bf[G][0], zro, 0, 0, 0);
#pragma unroll
            for (int kt = 1; kt < 4; ++kt)
#pragma unroll
                for (int G = 0; G < 4; ++G)
                    acc[G] = __builtin_amdgcn_mfma_f32_16x16x32_bf16(
                        af[kt], bf[G][kt], acc[G], 0, 0, 0);
#pragma unroll
            for (int G = 0; G < 4; ++G) {
                int n = G * 128 + jcol;
                uint2 pk;
                pk.x = (unsigned)f2bf(acc[G][0]) | ((unsigned)f2bf(acc[G][1]) << 16);
                pk.y = (unsigned)f2bf(acc[G][2]) | ((unsigned)f2bf(acc[G][3]) << 16);
                *(uint2*)(g2 + n * RP + rg * 16 + 4 * q) = pk;   // same wave reads it back
            }
        }
        // ---- Whh2 frags ----
        const short8* fr2 = (const short8*)((const char*)ws + 2 * FRAG_BYTES);
#pragma unroll
        for (int G = 0; G < 4; ++G)
#pragma unroll
            for (int kt = 0; kt < 4; ++kt)
                bf[G][kt] = fr2[((((G << 3) | wave) << 2) + kt) * 64 + lane];
    }

    // ---- Phase 2: LSTM2, 7 steps; FC2 runs on wave 7 ----
    // K-slots 100/101 retain phase-1 values (101=1.0 feeds bias folds; 100=stale x hits zero
    // weight rows). Pad cols: zero preacts -> hv=0 (garbage-free as in phase 1).
    const short8* w2fr = (const short8*)((const char*)ws + WS_W2_OFF);
    floatx4 yfc[RGn];
    if (wave == 7) {
#pragma unroll
        for (int rg = 0; rg < RGn; ++rg) yfc[rg] = zro;
    }

    for (int ps = 0; ps < Pn; ++ps) {
        int t = Tn + ps;
        const unsigned short* hc = (t & 1) ? hb1 : hb0;
        unsigned short* hn = (t & 1) ? hb0 : hb1;
        if (wave == 7) {
            if (ps >= 1) {   // hc holds h2 of step ps-1
                short8 w2f[4];
#pragma unroll
                for (int kt = 0; kt < 4; ++kt)
                    w2f[kt] = w2fr[((ps - 1) * 4 + kt) * 64 + lane];
#pragma unroll
                for (int rg = 0; rg < RGn; ++rg) {
                    short8 af2[4];
#pragma unroll
                    for (int kt = 0; kt < 4; ++kt)
                        af2[kt] = *(const short8*)(hc + (rg * 16 + l) * KP + kt * 32 + q * 8);
#pragma unroll
                    for (int kt = 0; kt < 4; ++kt)
                        yfc[rg] = __builtin_amdgcn_mfma_f32_16x16x32_bf16(
                            af2[kt], w2f[kt], yfc[rg], 0, 0, 0);
                }
            }
        } else {
#pragma unroll
            for (int rg = 0; rg < RGn; ++rg) {
                short8 af[4];
#pragma unroll
                for (int kt = 0; kt < 4; ++kt)
                    af[kt] = *(const short8*)(hc + (rg * 16 + l) * KP + kt * 32 + q * 8);
                floatx4 A0, A1, A2, A3;   // gates i, f, g, o; C-in = gin2 (bias2 + last·Wih2^T)
                {
                    uint2 p0 = *(const uint2*)(g2 + (0 * 128 + jcol) * RP + rg * 16 + 4 * q);
                    uint2 p1 = *(const uint2*)(g2 + (1 * 128 + jcol) * RP + rg * 16 + 4 * q);
                    uint2 p2 = *(const uint2*)(g2 + (2 * 128 + jcol) * RP + rg * 16 + 4 * q);
                    uint2 p3 = *(const uint2*)(g2 + (3 * 128 + jcol) * RP + rg * 16 + 4 * q);
                    A0[0] = __uint_as_float(p0.x << 16);
                    A0[1] = __uint_as_float(p0.x & 0xFFFF0000u);
                    A0[2] = __uint_as_float(p0.y << 16);
                    A0[3] = __uint_as_float(p0.y & 0xFFFF0000u);
                    A1[0] = __uint_as_float(p1.x << 16);
                    A1[1] = __uint_as_float(p1.x & 0xFFFF0000u);
                    A1[2] = __uint_as_float(p1.y << 16);
                    A1[3] = __uint_as_float(p1.y & 0xFFFF0000u);
                    A2[0] = __uint_as_float(p2.x << 16);
                    A2[1] = __uint_as_float(p2.x & 0xFFFF0000u);
                    A2[2] = __uint_as_float(p2.y << 16);
                    A2[3] = __uint_as_float(p2.y & 0xFFFF0000u);
                    A3[0] = __uint_as_float(p3.x << 16);
                    A3[1] = __uint_as_float(p3.x & 0xFFFF0000u);
                    A3[2] = __uint_as_float(p3.y << 16);
                    A3[3] = __uint_as_float(p3.y & 0xFFFF0000u);
                }
#pragma unroll
                for (int kt = 0; kt < 4; ++kt) {
                    A0 = __builtin_amdgcn_mfma_f32_16x16x32_bf16(af[kt], bf[0][kt], A0, 0, 0, 0);
                    A1 = __builtin_amdgcn_mfma_f32_16x16x32_bf16(af[kt], bf[1][kt], A1, 0, 0, 0);
                    A2 = __builtin_amdgcn_mfma_f32_16x16x32_bf16(af[kt], bf[2][kt], A2, 0, 0, 0);
                    A3 = __builtin_amdgcn_mfma_f32_16x16x32_bf16(af[kt], bf[3][kt], A3, 0, 0, 0);
                }
#pragma unroll
                for (int r = 0; r < 4; ++r) {
                    float ei = e2_(-A0[r]);
                    float eg = e2_(A2[r]);
                    float t1 = 1.f + ei;
                    float pc = (eg - 1.f) * rcp_(fmaf(t1, eg, t1));
                    float ef = e2_(-A1[r]);
                    float cc = fmaf(cst[rg][r], rcp_(1.f + ef), pc);
                    cst[rg][r] = cc;
                    float eo = e2_(-A3[r]);
                    float ec = e2_(cc * LOG2E2);
                    float t2 = 1.f + eo;
                    float hv = (ec - 1.f) * rcp_(fmaf(t2, ec, t2));
                    if (wr)
                        hn[(rg * 16 + 4 * q + r) * KP + jcol] = f2bf(hv);   // ps=6 too
                }
            }
        }
        __syncthreads();
    }

    // ---- final FC2 for h2 of ps=6 (t=36 even -> hn=hb1); b2 folded (scaled) into ps=6 k=101 ----
    if (wave == 7) {
        short8 w2f[4];
#pragma unroll
        for (int kt = 0; kt < 4; ++kt)
            w2f[kt] = w2fr[(6 * 4 + kt) * 64 + lane];
#pragma unroll
        for (int rg = 0; rg < RGn; ++rg) {
            short8 af2[4];
#pragma unroll
            for (int kt = 0; kt < 4; ++kt)
                af2[kt] = *(const short8*)(hb1 + (rg * 16 + l) * KP + kt * 32 + q * 8);
#pragma unroll
            for (int kt = 0; kt < 4; ++kt)
                yfc[rg] = __builtin_amdgcn_mfma_f32_16x16x32_bf16(
                    af2[kt], w2f[kt], yfc[rg], 0, 0, 0);
            if (l < Pn) {
#pragma unroll
                for (int r = 0; r < 4; ++r)   // y is log2e-scaled: sig = 1/(1+2^-y')
                    out[(rowbase + rg * 16 + 4 * q + r) * Pn + l] =
                        rcp_(1.f + e2_(-yfc[rg][r]));
            }
        }
    }
}

extern "C" void kernel_launch(void* const* d_in, const int* in_sizes, int n_in,
                              void* d_out, int out_size, void* d_ws, size_t ws_size,
                              hipStream_t stream) {
    const float* x    = (const float*)d_in[0];
    const float* W1   = (const float*)d_in[1];
    const float* b1   = (const float*)d_in[2];
    const float* Wih1 = (const float*)d_in[3];
    const float* Whh1 = (const float*)d_in[4];
    const float* bih1 = (const float*)d_in[5];
    const float* bhh1 = (const float*)d_in[6];
    const float* Wih2 = (const float*)d_in[7];
    const float* Whh2 = (const float*)d_in[8];
    const float* bih2 = (const float*)d_in[9];
    const float* bhh2 = (const float*)d_in[10];
    const float* W2   = (const float*)d_in[11];
    const float* b2   = (const float*)d_in[12];
    float* out = (float*)d_out;
    float* ws  = (float*)d_ws;

    (void)hipFuncSetAttribute((const void*)lstm_fused,
                              hipFuncAttributeMaxDynamicSharedMemorySize, SMEM_BYTES);

    setup_kernel<<<PACK_BLOCKS, 256, 0, stream>>>(W1, b1, Wih1, bih1, bhh1,
                                                  bih2, bhh2, Whh1, Wih2, Whh2, W2, b2, ws);
    lstm_fused<<<Bn / ROWS, 512, SMEM_BYTES, stream>>>(x, ws, out);
}